// Round 4
// baseline (5672.237 us; speedup 1.0000x reference)
//
#include <hip/hip_runtime.h>
#include <hip/hip_bf16.h>
#include <string.h>

typedef __bf16 bf16x8 __attribute__((ext_vector_type(8)));
typedef float f32x4 __attribute__((ext_vector_type(4)));

#define MFMA16(a, b, c) __builtin_amdgcn_mfma_f32_16x16x32_bf16((a), (b), (c), 0, 0, 0)

#define BB 64
#define TT 256
#define II 512
#define SS 256
#define DD 1024
#define HH 1024

// ---- ws layout (bytes); total ~42.3 MB (<= 43.02 MB proven) ----------------
#define OFF_A ((size_t)0)           // 32MB bf16 activation slot (a0, then a2)
#define OFF_Z ((size_t)33554432)    // 8MB bf16 z archive (T,B,S)
#define OFF_HB ((size_t)41943040)   // bf16 [2][64][1024] h handoff (2B WT stores)
#define OFF_ZB ((size_t)42205184)   // bf16 [64][256] z handoff
#define OFF_CNT ((size_t)42237952)  // int hflag[256] | zflag[256]

// ---- d_out (fp32, 66,977,792 B) scratch layout -----------------------------
// [0,32MB): h_all bf16  (dead after dec0 -> a1 bf16)
// [34MB,42MB): xm bf16 (T,B,S)  [42MB,50MB): xv bf16 (T,B,S) (dead after scan)
// [50MB,56.5MB): bf16 dec weights W0/W1/W2 (dead before k_dec3 writes outputs)
#define DO_XM ((size_t)35651584)
#define DO_XV ((size_t)44040192)
#define DO_WB0 ((size_t)52428800)  // 1024*1280 bf16 = 2,621,440 B
#define DO_WB1 ((size_t)55050240)  // 1024*1024 bf16 = 2,097,152 B
#define DO_WB2 ((size_t)57147392)  // 1024*1024 bf16 = 2,097,152 B (ends 59,244,544)
#define OUTD_ELEMS 8355840  // 64*255*512

#define NGRU 64  // GRU blocks (16 h-cols each) — halved producers/pollers
#define NPST 8   // posterior blocks (32 z-cols each)

__device__ __forceinline__ float fsig(float x) { return 1.f / (1.f + __expf(-x)); }
__device__ __forceinline__ float ftanh(float x) {
  float ax = __builtin_fabsf(x);
  float e = __expf(-2.f * ax);
  float r = (1.f - e) / (1.f + e);
  return __builtin_copysignf(r, x);
}

__device__ __forceinline__ bf16x8 ld8f(const float* p) {
  float4 a = *(const float4*)p;
  float4 b = *(const float4*)(p + 4);
  bf16x8 r;
  r[0] = (__bf16)a.x; r[1] = (__bf16)a.y; r[2] = (__bf16)a.z; r[3] = (__bf16)a.w;
  r[4] = (__bf16)b.x; r[5] = (__bf16)b.y; r[6] = (__bf16)b.z; r[7] = (__bf16)b.w;
  return r;
}

// ---- sync: per-block flag array; relaxed poll + one acquire (L2 inv) -------
// (r2 lesson: coherent-atomic data loads bypass L2 and regress 2us/step;
//  plain loads + a single acquire-inv share one L2 fill per XCD — keep that.)
__device__ __forceinline__ void wait_flags(int* flags, int n, int target, bool acq) {
  if ((int)threadIdx.x < n) {
    while (__hip_atomic_load(flags + threadIdx.x, __ATOMIC_RELAXED, __HIP_MEMORY_SCOPE_AGENT) <
           target)
      __builtin_amdgcn_s_sleep(1);
  }
  __syncthreads();
  if (acq) {
    if (threadIdx.x == 0)
      (void)__hip_atomic_load(flags, __ATOMIC_ACQUIRE, __HIP_MEMORY_SCOPE_AGENT);  // one inv
    __syncthreads();
  }
}
// 2-byte write-through (agent-relaxed) store of a bf16
__device__ __forceinline__ void st2(__bf16* p, float v) {
  __bf16 hv = (__bf16)v;
  unsigned short ub;
  __builtin_memcpy(&ub, &hv, 2);
  __hip_atomic_store((unsigned short*)p, ub, __ATOMIC_RELAXED, __HIP_MEMORY_SCOPE_AGENT);
}

// ---------------------------------------------------------------------------
// k_xmv: xm/xv = x @ Wm[:, :I].T, x @ Wv[:, :I].T -> bf16 into d_out scratch.
// Also zeroes the scan flags and converts dec weights W0/W1/W2 to bf16.
// ---------------------------------------------------------------------------
__global__ __launch_bounds__(256) void k_xmv(const float* __restrict__ x,
                                             const float* __restrict__ Wm,
                                             const float* __restrict__ Wv,
                                             const float* __restrict__ Wd0,
                                             const float* __restrict__ Wd1,
                                             const float* __restrict__ Wd2,
                                             char* __restrict__ doutc, char* __restrict__ ws) {
  if (blockIdx.x == 0 && blockIdx.y == 0) {
    int* cnt = (int*)(ws + OFF_CNT);
    cnt[threadIdx.x] = 0;
    cnt[threadIdx.x + 256] = 0;
  }
  // ---- fold-in: fp32 -> bf16 weight conversion (W0:1,310,720 W1/W2:1,048,576 elems)
  {
    size_t lin = (size_t)blockIdx.y * 256 + blockIdx.x;  // 0..2047
    size_t g = (lin * 256 + threadIdx.x) * 8;            // 8 elems/thread
    if (g < 3407872) {
      const float* src;
      __bf16* dst;
      if (g < 1310720) {
        src = Wd0 + g;
        dst = (__bf16*)(doutc + DO_WB0) + g;
      } else if (g < 2359296) {
        src = Wd1 + (g - 1310720);
        dst = (__bf16*)(doutc + DO_WB1) + (g - 1310720);
      } else {
        src = Wd2 + (g - 2359296);
        dst = (__bf16*)(doutc + DO_WB2) + (g - 2359296);
      }
      *(bf16x8*)dst = ld8f(src);
    }
  }
  __bf16* xm = (__bf16*)(doutc + DO_XM);
  __bf16* xv = (__bf16*)(doutc + DO_XV);

  int m0 = blockIdx.x * 64, n0 = blockIdx.y * 64;
  int tid = threadIdx.x, lane = tid & 63, wv = tid >> 6;
  int n15 = lane & 15, q8 = (lane >> 4) * 8;

  int row = m0 + wv * 16 + n15;  // m = t*64 + b
  int t = row >> 6, b = row & 63;
  const float* arow = x + ((size_t)(b * TT + t)) * II + q8;

  const float* brow[4];
#pragma unroll
  for (int j = 0; j < 4; ++j) {
    int c = n0 + j * 16 + n15;
    brow[j] = ((c < SS) ? (Wm + (size_t)c * (II + DD)) : (Wv + (size_t)(c - SS) * (II + DD))) + q8;
  }
  f32x4 acc[4] = {};
#pragma unroll 4
  for (int k = 0; k < II; k += 32) {
    bf16x8 a = ld8f(arow + k);
#pragma unroll
    for (int j = 0; j < 4; ++j) acc[j] = MFMA16(a, ld8f(brow[j] + k), acc[j]);
  }
  int mb = m0 + wv * 16 + (lane >> 4) * 4;
#pragma unroll
  for (int j = 0; j < 4; ++j) {
    int c = n0 + j * 16 + n15;
    __bf16* dst = (c < SS) ? (xm + c) : (xv + (c - SS));
#pragma unroll
    for (int r = 0; r < 4; ++r) dst[(size_t)(mb + r) * SS] = (__bf16)acc[j][r];
  }
}

// ---------------------------------------------------------------------------
// k_scan v6: 64 GRU blocks x 16 cols (120KB LDS) + 8 posterior x 32 cols
// (128KB LDS). Halved producers/flags, quartered poll traffic vs v4 — the
// 16-col GRU tile uses all 16 MFMA columns (v4's 8-col tile wasted half the
// lanes), so per-wave MFMA count is unchanged. Handoff reads: plain bf16x8
// loads after one acquire-inv (proven r1). Archive stores after signal,
// nontemporal (off critical path).
// ---------------------------------------------------------------------------
__global__ __launch_bounds__(256, 1) void k_scan(
    const float* __restrict__ Wih, const float* __restrict__ Whh,
    const float* __restrict__ bih, const float* __restrict__ bhh,
    const float* __restrict__ Wm, const float* __restrict__ bm,
    const float* __restrict__ Wv, const float* __restrict__ bv,
    const float* __restrict__ noise, char* __restrict__ ws, char* __restrict__ doutc) {
  __shared__ __bf16 smem[65536];  // 128 KB

  __bf16* hbL[2] = {(__bf16*)(ws + OFF_HB), (__bf16*)(ws + OFF_HB) + (size_t)BB * DD};
  __bf16* zb = (__bf16*)(ws + OFF_ZB);
  __bf16* z_all = (__bf16*)(ws + OFF_Z);
  __bf16* h_all = (__bf16*)doutc;
  const __bf16* xm = (const __bf16*)(doutc + DO_XM);
  const __bf16* xv = (const __bf16*)(doutc + DO_XV);
  int* hflag = (int*)(ws + OFF_CNT);
  int* zflag = hflag + 256;

  int blk = blockIdx.x, tid = threadIdx.x, lane = tid & 63, wv = tid >> 6;
  int n15 = lane & 15, q = lane >> 4, q8 = q * 8, q4 = q * 4;
  const int rb = wv * 16 + n15;  // A-fragment batch row
  int swq = (q + ((n15 >> 1) & 3)) & 3;  // bank swizzle (<=2-way, free)

  if (blk < NGRU) {
    int c0 = blk * 16;
    // ---- stage W_hh (3 gates x 16 cols x K=1024) into LDS [0,49152) elts
    for (int u = tid; u < 6144; u += 256) {
      int qq = u & 3, col = (u >> 2) & 15, kk = (u >> 6) & 31, g = u >> 11;
      int sq = (qq + ((col >> 1) & 3)) & 3;
      *(bf16x8*)(smem + ((((g * 32 + kk) * 16 + col) * 4) + sq) * 8) =
          ld8f(Whh + ((size_t)(g * DD + c0 + col)) * DD + kk * 32 + qq * 8);
    }
    // ---- stage W_ih (3 gates x 16 cols x K=256) into LDS [49152,61440) elts
    for (int u = tid; u < 1536; u += 256) {
      int qq = u & 3, col = (u >> 2) & 15, kk = (u >> 6) & 7, g = u >> 9;
      int sq = (qq + ((col >> 1) & 3)) & 3;
      *(bf16x8*)(smem + 49152 + ((((g * 8 + kk) * 16 + col) * 4) + sq) * 8) =
          ld8f(Wih + ((size_t)(g * DD + c0 + col)) * SS + kk * 32 + qq * 8);
    }
    __syncthreads();

    int ccb = c0 + n15;  // output col — all 16 lanes distinct now
    float brs = bih[ccb] + bhh[ccb];
    float bzs = bih[DD + ccb] + bhh[DD + ccb];
    float bin = bih[2 * DD + ccb];
    float bhn = bhh[2 * DD + ccb];
    f32x4 hcarry = {};  // fp32 h for rows mb..mb+3, col ccb — registers!
    int mb = wv * 16 + q4;

    for (int t = 0; t < TT; ++t) {
      f32x4 accr = {}, accz = {}, acchn = {}, accin = {};
      if (t > 0) {
        wait_flags(hflag, NGRU, t, true);  // h_{t-1} ready
        const __bf16* hp = hbL[t & 1] + (size_t)rb * DD + q8;
        bf16x8 hA[32];
#pragma unroll
        for (int kk = 0; kk < 32; ++kk) hA[kk] = *(const bf16x8*)(hp + kk * 32);
#pragma unroll
        for (int kk = 0; kk < 32; ++kk) {
          const __bf16* wb = smem + ((size_t)kk * 16 + n15) * 32 + swq * 8;
          accr = MFMA16(hA[kk], *(const bf16x8*)(wb), accr);
          accz = MFMA16(hA[kk], *(const bf16x8*)(wb + 16384), accz);
          acchn = MFMA16(hA[kk], *(const bf16x8*)(wb + 32768), acchn);
        }
        wait_flags(zflag, NPST, t, false);  // z_{t-1}; h-acquire already inv'd zb lines
        const __bf16* zp = zb + (size_t)rb * SS + q8;
        bf16x8 zA[8];
#pragma unroll
        for (int kk = 0; kk < 8; ++kk) zA[kk] = *(const bf16x8*)(zp + kk * 32);
#pragma unroll
        for (int kk = 0; kk < 8; ++kk) {
          const __bf16* wb = smem + 49152 + ((size_t)kk * 16 + n15) * 32 + swq * 8;
          accr = MFMA16(zA[kk], *(const bf16x8*)(wb), accr);
          accz = MFMA16(zA[kk], *(const bf16x8*)(wb + 4096), accz);
          accin = MFMA16(zA[kk], *(const bf16x8*)(wb + 8192), accin);
        }
      }
      __bf16* hw = hbL[(t + 1) & 1];
      __bf16* hall_t = h_all + (size_t)t * BB * DD;
#pragma unroll
      for (int r = 0; r < 4; ++r) {
        int mm = mb + r;
        float rg = fsig(accr[r] + brs);
        float zg = fsig(accz[r] + bzs);
        float ng = ftanh(accin[r] + bin + rg * (acchn[r] + bhn));
        float hn = (1.f - zg) * ng + zg * hcarry[r];
        hcarry[r] = hn;
        st2(hw + (size_t)mm * DD + ccb, hn);  // handoff (write-through)
      }
      // signal: drain handoff stores, barrier, one uncontended flag store
      asm volatile("s_waitcnt vmcnt(0)" ::: "memory");
      __syncthreads();
      if (tid == 0)
        __hip_atomic_store(hflag + blk, t + 1, __ATOMIC_RELAXED, __HIP_MEMORY_SCOPE_AGENT);
      // archive AFTER signal: latency hides under next-step wait
#pragma unroll
      for (int r = 0; r < 4; ++r)
        __builtin_nontemporal_store((__bf16)hcarry[r], hall_t + (size_t)(mb + r) * DD + ccb);
    }
  } else {
    int p = blk - NGRU, cp0 = p * 32;
    // ---- stage Wm/Wv h-part (2 x 32 cols x K=1024) into LDS (128 KB)
    for (int u = tid; u < 8192; u += 256) {
      int qq = u & 3, col = (u >> 2) & 31, kk = (u >> 7) & 31, mv = u >> 12;
      int sq = (qq + ((col >> 1) & 3)) & 3;
      const float* src = (mv ? Wv : Wm) + ((size_t)(cp0 + col)) * (II + DD) + II + kk * 32 + qq * 8;
      *(bf16x8*)(smem + ((((mv * 32 + kk) * 32 + col) * 4) + sq) * 8) = ld8f(src);
    }
    __syncthreads();

    int c2a = cp0 + n15, c2b = cp0 + 16 + n15;
    float bmv0 = bm[c2a], bvv0 = bv[c2a];
    float bmv1 = bm[c2b], bvv1 = bv[c2b];
    int mb = wv * 16 + q4;

    for (int t = 0; t < TT; ++t) {
      wait_flags(hflag, NGRU, t + 1, true);  // h_t ready
      const __bf16* hp = hbL[(t + 1) & 1] + (size_t)rb * DD + q8;
      bf16x8 hA[32];
#pragma unroll
      for (int kk = 0; kk < 32; ++kk) hA[kk] = *(const bf16x8*)(hp + kk * 32);
      f32x4 am[2] = {}, av[2] = {};
#pragma unroll
      for (int kk = 0; kk < 32; ++kk) {
#pragma unroll
        for (int jt = 0; jt < 2; ++jt) {
          const __bf16* wb = smem + ((size_t)kk * 32 + jt * 16 + n15) * 32 + swq * 8;
          am[jt] = MFMA16(hA[kk], *(const bf16x8*)(wb), am[jt]);
          av[jt] = MFMA16(hA[kk], *(const bf16x8*)(wb + 32768), av[jt]);
        }
      }
      f32x4 zs[2];
#pragma unroll
      for (int jt = 0; jt < 2; ++jt) {
        int c2 = jt ? c2b : c2a;
        float bmv = jt ? bmv1 : bmv0, bvv = jt ? bvv1 : bvv0;
#pragma unroll
        for (int r = 0; r < 4; ++r) {
          int mm = mb + r;
          size_t gidx = ((size_t)t * BB + mm) * SS + c2;
          float mean = am[jt][r] + bmv + (float)xm[gidx];
          float vr = av[jt][r] + bvv + (float)xv[gidx];
          float sd = __expf(0.5f * vr);
          float zt = noise[gidx] * sd + mean;
          zs[jt][r] = zt;
          st2(zb + (size_t)mm * SS + c2, zt);  // handoff
        }
      }
      asm volatile("s_waitcnt vmcnt(0)" ::: "memory");
      __syncthreads();
      if (tid == 0)
        __hip_atomic_store(zflag + p, t + 1, __ATOMIC_RELAXED, __HIP_MEMORY_SCOPE_AGENT);
      // archive AFTER signal (nontemporal)
#pragma unroll
      for (int jt = 0; jt < 2; ++jt) {
        int c2 = jt ? c2b : c2a;
#pragma unroll
        for (int r = 0; r < 4; ++r)
          __builtin_nontemporal_store((__bf16)zs[jt][r],
                                      z_all + ((size_t)t * BB + mb + r) * SS + c2);
      }
    }
  }
}

// ---------------------------------------------------------------------------
// Decoder layer 0: elu([h_all | z_all] @ W0.T + b0) -> a0 (ws), K=1280.
// ---------------------------------------------------------------------------
__global__ __launch_bounds__(256, 2) void k_dec0(const char* __restrict__ doutc,
                                                 const char* __restrict__ ws,
                                                 const float* __restrict__ b0,
                                                 __bf16* __restrict__ C) {
  const __bf16* h_all = (const __bf16*)doutc;
  const __bf16* z_all = (const __bf16*)(ws + OFF_Z);
  const __bf16* W0b = (const __bf16*)(doutc + DO_WB0);
  int m0 = blockIdx.x * 128, n0 = blockIdx.y * 128;
  int tid = threadIdx.x, lane = tid & 63, w = tid >> 6;
  int wm = w >> 1, wn = w & 1;
  int n15 = lane & 15, q8 = (lane >> 4) * 8, q4 = (lane >> 4) * 4;

  const __bf16* hrow[4];
  const __bf16* zrow[4];
  const __bf16* brow[4];
#pragma unroll
  for (int i = 0; i < 4; ++i) {
    int row = m0 + wm * 64 + i * 16 + n15;  // m = b*256 + t
    int b = row >> 8, tq = row & 255;
    hrow[i] = h_all + ((size_t)tq * BB + b) * DD + q8;
    zrow[i] = z_all + ((size_t)tq * BB + b) * SS + q8;
  }
#pragma unroll
  for (int j = 0; j < 4; ++j)
    brow[j] = W0b + (size_t)(n0 + wn * 64 + j * 16 + n15) * (DD + SS) + q8;

  f32x4 acc[4][4] = {};
  for (int k = 0; k < DD + SS; k += 32) {
    bf16x8 af[4], bfv[4];
#pragma unroll
    for (int i = 0; i < 4; ++i)
      af[i] = (k < DD) ? *(const bf16x8*)(hrow[i] + k) : *(const bf16x8*)(zrow[i] + k - DD);
#pragma unroll
    for (int j = 0; j < 4; ++j) bfv[j] = *(const bf16x8*)(brow[j] + k);
#pragma unroll
    for (int i = 0; i < 4; ++i)
#pragma unroll
      for (int j = 0; j < 4; ++j) acc[i][j] = MFMA16(af[i], bfv[j], acc[i][j]);
  }
#pragma unroll
  for (int i = 0; i < 4; ++i) {
    int mr = m0 + wm * 64 + i * 16 + q4;
#pragma unroll
    for (int j = 0; j < 4; ++j) {
      int c = n0 + wn * 64 + j * 16 + n15;
      float bb = b0[c];
#pragma unroll
      for (int r = 0; r < 4; ++r) {
        float v = acc[i][j][r] + bb;
        v = v > 0.f ? v : (__expf(v) - 1.f);
        C[(size_t)(mr + r) * HH + c] = (__bf16)v;
      }
    }
  }
}

// ---------------------------------------------------------------------------
// Decoder mid layer: C = elu(A @ W.T + b), K = N = 1024; W pre-converted bf16.
// ---------------------------------------------------------------------------
__global__ __launch_bounds__(256, 2) void k_dec_mid(const __bf16* __restrict__ A,
                                                    const __bf16* __restrict__ W,
                                                    const float* __restrict__ bias,
                                                    __bf16* __restrict__ C) {
  int m0 = blockIdx.x * 128, n0 = blockIdx.y * 128;
  int tid = threadIdx.x, lane = tid & 63, w = tid >> 6;
  int wm = w >> 1, wn = w & 1;
  int n15 = lane & 15, q8 = (lane >> 4) * 8, q4 = (lane >> 4) * 4;

  const __bf16* arow[4];
  const __bf16* brow[4];
#pragma unroll
  for (int i = 0; i < 4; ++i) arow[i] = A + (size_t)(m0 + wm * 64 + i * 16 + n15) * DD + q8;
#pragma unroll
  for (int j = 0; j < 4; ++j) brow[j] = W + (size_t)(n0 + wn * 64 + j * 16 + n15) * DD + q8;

  f32x4 acc[4][4] = {};
  for (int k = 0; k < DD; k += 32) {
    bf16x8 af[4], bfv[4];
#pragma unroll
    for (int i = 0; i < 4; ++i) af[i] = *(const bf16x8*)(arow[i] + k);
#pragma unroll
    for (int j = 0; j < 4; ++j) bfv[j] = *(const bf16x8*)(brow[j] + k);
#pragma unroll
    for (int i = 0; i < 4; ++i)
#pragma unroll
      for (int j = 0; j < 4; ++j) acc[i][j] = MFMA16(af[i], bfv[j], acc[i][j]);
  }
#pragma unroll
  for (int i = 0; i < 4; ++i) {
    int mr = m0 + wm * 64 + i * 16 + q4;
#pragma unroll
    for (int j = 0; j < 4; ++j) {
      int c = n0 + wn * 64 + j * 16 + n15;
      float bb = bias[c];
#pragma unroll
      for (int r = 0; r < 4; ++r) {
        float v = acc[i][j][r] + bb;
        v = v > 0.f ? v : (__expf(v) - 1.f);
        C[(size_t)(mr + r) * HH + c] = (__bf16)v;
      }
    }
  }
}

// ---------------------------------------------------------------------------
// Decoder layer 3 + output assembly (fp32 outputs)
// ---------------------------------------------------------------------------
__global__ __launch_bounds__(256, 2) void k_dec3(const __bf16* __restrict__ A,
                                                 const float* __restrict__ W3,
                                                 const float* __restrict__ b3,
                                                 const float* __restrict__ x,
                                                 float* __restrict__ outd,
                                                 float* __restrict__ outh) {
  int m0 = blockIdx.x * 128, n0 = blockIdx.y * 128;
  int tid = threadIdx.x, lane = tid & 63, w = tid >> 6;
  int wm = w >> 1, wn = w & 1;
  int n15 = lane & 15, q8 = (lane >> 4) * 8, q4 = (lane >> 4) * 4;

  const __bf16* arow[4];
  const float* brow[4];
#pragma unroll
  for (int i = 0; i < 4; ++i) arow[i] = A + (size_t)(m0 + wm * 64 + i * 16 + n15) * HH + q8;
#pragma unroll
  for (int j = 0; j < 4; ++j) brow[j] = W3 + (size_t)(n0 + wn * 64 + j * 16 + n15) * HH + q8;

  f32x4 acc[4][4] = {};
  for (int k = 0; k < HH; k += 32) {
    bf16x8 af[4], bfv[4];
#pragma unroll
    for (int i = 0; i < 4; ++i) af[i] = *(const bf16x8*)(arow[i] + k);
#pragma unroll
    for (int j = 0; j < 4; ++j) bfv[j] = ld8f(brow[j] + k);
#pragma unroll
    for (int i = 0; i < 4; ++i)
#pragma unroll
      for (int j = 0; j < 4; ++j) acc[i][j] = MFMA16(af[i], bfv[j], acc[i][j]);
  }
#pragma unroll
  for (int i = 0; i < 4; ++i) {
    int mr = m0 + wm * 64 + i * 16 + q4;
#pragma unroll
    for (int j = 0; j < 4; ++j) {
      int c = n0 + wn * 64 + j * 16 + n15;
      float b3v = b3[c];
#pragma unroll
      for (int r = 0; r < 4; ++r) {
        int mm = mr + r;
        int b = mm >> 8, tq = mm & 255;
        float dv = acc[i][j][r] + b3v;
        if (tq < 255) {
          outd[((size_t)b * 255 + tq) * II + c] = dv;
          outh[((size_t)b * TT + tq + 1) * II + c] = x[((size_t)b * TT + tq) * II + c] + dv;
        }
        if (tq == 0) outh[((size_t)b * TT) * II + c] = x[((size_t)b * TT) * II + c];
      }
    }
  }
}

// ---------------------------------------------------------------------------
extern "C" void kernel_launch(void* const* d_in, const int* in_sizes, int n_in,
                              void* d_out, int out_size, void* d_ws, size_t ws_size,
                              hipStream_t stream) {
  const float* x = (const float*)d_in[0];
  const float* noise = (const float*)d_in[1];
  const float* W_ih = (const float*)d_in[2];
  const float* W_hh = (const float*)d_in[3];
  const float* b_ih = (const float*)d_in[4];
  const float* b_hh = (const float*)d_in[5];
  const float* Wm = (const float*)d_in[6];
  const float* bm = (const float*)d_in[7];
  const float* Wv = (const float*)d_in[8];
  const float* bv = (const float*)d_in[9];
  const float* dW0 = (const float*)d_in[10];
  const float* db0 = (const float*)d_in[11];
  const float* dW1 = (const float*)d_in[12];
  const float* db1 = (const float*)d_in[13];
  const float* dW2 = (const float*)d_in[14];
  const float* db2 = (const float*)d_in[15];
  const float* dW3 = (const float*)d_in[16];
  const float* db3 = (const float*)d_in[17];

  char* ws = (char*)d_ws;
  char* doutc = (char*)d_out;
  __bf16* a0 = (__bf16*)(ws + OFF_A);  // dec0 out
  __bf16* a1 = (__bf16*)doutc;         // dec1 out (over dead h_all)
  __bf16* a2 = (__bf16*)(ws + OFF_A);  // dec2 out (over dead a0)

  // 1) x-dependent posterior halves + flag zeroing + dec-weight bf16 staging
  k_xmv<<<dim3(256, 8), 256, 0, stream>>>(x, Wm, Wv, dW0, dW1, dW2, doutc, ws);

  // 2) persistent scan: 64 GRU + 8 posterior blocks, all weights in LDS
  k_scan<<<NGRU + NPST, 256, 0, stream>>>(W_ih, W_hh, b_ih, b_hh, Wm, bm, Wv, bv, noise, ws,
                                          doutc);

  // 3) decoder (W0/W1/W2 consumed as bf16 from d_out scratch; dead before dec3)
  k_dec0<<<dim3(128, 8), 256, 0, stream>>>(doutc, ws, db0, a0);
  k_dec_mid<<<dim3(128, 8), 256, 0, stream>>>(a0, (const __bf16*)(doutc + DO_WB1), db1, a1);
  k_dec_mid<<<dim3(128, 8), 256, 0, stream>>>(a1, (const __bf16*)(doutc + DO_WB2), db2, a2);
  k_dec3<<<dim3(128, 4), 256, 0, stream>>>(a2, dW3, db3, x, (float*)doutc,
                                           (float*)doutc + OUTD_ELEMS);
}

// Round 5
// 4309.636 us; speedup vs baseline: 1.3162x; 1.3162x over previous
//
#include <hip/hip_runtime.h>
#include <hip/hip_bf16.h>
#include <string.h>

typedef __bf16 bf16x8 __attribute__((ext_vector_type(8)));
typedef float f32x4 __attribute__((ext_vector_type(4)));

#define MFMA16(a, b, c) __builtin_amdgcn_mfma_f32_16x16x32_bf16((a), (b), (c), 0, 0, 0)

#define BB 64
#define TT 256
#define II 512
#define SS 256
#define DD 1024
#define HH 1024

// ---- ws layout (bytes); total ~42.3 MB (<= 43.02 MB proven) ----------------
#define OFF_A ((size_t)0)           // 32MB bf16 activation slot (a0, then a2)
#define OFF_Z ((size_t)33554432)    // 8MB bf16 z archive (T,B,S)
#define OFF_HB ((size_t)41943040)   // bf16 [2][64][1024] h handoff (2B WT stores)
#define OFF_ZB ((size_t)42205184)   // bf16 [64][256] z handoff
#define OFF_CNT ((size_t)42237952)  // int hflag[256] | zflag[256]

// ---- d_out (fp32, 66,977,792 B) scratch layout -----------------------------
// [0,32MB): h_all bf16  (dead after dec0 -> a1 bf16)
// [34MB,42MB): xm bf16 (T,B,S)  [42MB,50MB): xv bf16 (T,B,S) (dead after scan)
// [50MB,56.5MB): bf16 dec weights W0/W1/W2 (dead before k_dec3 writes outputs)
#define DO_XM ((size_t)35651584)
#define DO_XV ((size_t)44040192)
#define DO_WB0 ((size_t)52428800)  // 1024*1280 bf16 = 2,621,440 B
#define DO_WB1 ((size_t)55050240)  // 1024*1024 bf16 = 2,097,152 B
#define DO_WB2 ((size_t)57147392)  // 1024*1024 bf16 = 2,097,152 B (ends 59,244,544)
#define OUTD_ELEMS 8355840  // 64*255*512

#define NGRU 128  // GRU blocks (8 h-cols each) — R1-proven structure
#define NPST 16   // posterior blocks (16 z-cols each)

__device__ __forceinline__ float fsig(float x) { return 1.f / (1.f + __expf(-x)); }
__device__ __forceinline__ float ftanh(float x) {
  float ax = __builtin_fabsf(x);
  float e = __expf(-2.f * ax);
  float r = (1.f - e) / (1.f + e);
  return __builtin_copysignf(r, x);
}

__device__ __forceinline__ bf16x8 ld8f(const float* p) {
  float4 a = *(const float4*)p;
  float4 b = *(const float4*)(p + 4);
  bf16x8 r;
  r[0] = (__bf16)a.x; r[1] = (__bf16)a.y; r[2] = (__bf16)a.z; r[3] = (__bf16)a.w;
  r[4] = (__bf16)b.x; r[5] = (__bf16)b.y; r[6] = (__bf16)b.z; r[7] = (__bf16)b.w;
  return r;
}

// ---- sync: per-block flag array; relaxed poll + one acquire (L2 inv) -------
// (R2 lesson: coherent-atomic DATA loads bypass L2 -> regress; plain loads
//  after one acquire share one L2 fill per XCD. R4 lesson: fewer/larger
//  blocks do NOT help — contention was never the limit.)
__device__ __forceinline__ void wait_flags(int* flags, int n, int target, bool acq) {
  if ((int)threadIdx.x < n) {
    while (__hip_atomic_load(flags + threadIdx.x, __ATOMIC_RELAXED, __HIP_MEMORY_SCOPE_AGENT) <
           target)
      __builtin_amdgcn_s_sleep(1);
  }
  __syncthreads();
  if (acq) {
    if (threadIdx.x == 0)
      (void)__hip_atomic_load(flags, __ATOMIC_ACQUIRE, __HIP_MEMORY_SCOPE_AGENT);  // one inv
    __syncthreads();
  }
}
// 2-byte write-through (agent-relaxed) store of a bf16
__device__ __forceinline__ void st2(__bf16* p, float v) {
  __bf16 hv = (__bf16)v;
  unsigned short ub;
  __builtin_memcpy(&ub, &hv, 2);
  __hip_atomic_store((unsigned short*)p, ub, __ATOMIC_RELAXED, __HIP_MEMORY_SCOPE_AGENT);
}

// ---------------------------------------------------------------------------
// k_xmv: xm/xv = x @ Wm[:, :I].T, x @ Wv[:, :I].T -> bf16 into d_out scratch.
// Also zeroes the scan flags and converts dec weights W0/W1/W2 to bf16.
// ---------------------------------------------------------------------------
__global__ __launch_bounds__(256) void k_xmv(const float* __restrict__ x,
                                             const float* __restrict__ Wm,
                                             const float* __restrict__ Wv,
                                             const float* __restrict__ Wd0,
                                             const float* __restrict__ Wd1,
                                             const float* __restrict__ Wd2,
                                             char* __restrict__ doutc, char* __restrict__ ws) {
  if (blockIdx.x == 0 && blockIdx.y == 0) {
    int* cnt = (int*)(ws + OFF_CNT);
    cnt[threadIdx.x] = 0;
    cnt[threadIdx.x + 256] = 0;
  }
  // ---- fold-in: fp32 -> bf16 weight conversion (W0:1,310,720 W1/W2:1,048,576 elems)
  {
    size_t lin = (size_t)blockIdx.y * 256 + blockIdx.x;  // 0..2047
    size_t g = (lin * 256 + threadIdx.x) * 8;            // 8 elems/thread
    if (g < 3407872) {
      const float* src;
      __bf16* dst;
      if (g < 1310720) {
        src = Wd0 + g;
        dst = (__bf16*)(doutc + DO_WB0) + g;
      } else if (g < 2359296) {
        src = Wd1 + (g - 1310720);
        dst = (__bf16*)(doutc + DO_WB1) + (g - 1310720);
      } else {
        src = Wd2 + (g - 2359296);
        dst = (__bf16*)(doutc + DO_WB2) + (g - 2359296);
      }
      *(bf16x8*)dst = ld8f(src);
    }
  }
  __bf16* xm = (__bf16*)(doutc + DO_XM);
  __bf16* xv = (__bf16*)(doutc + DO_XV);

  int m0 = blockIdx.x * 64, n0 = blockIdx.y * 64;
  int tid = threadIdx.x, lane = tid & 63, wv = tid >> 6;
  int n15 = lane & 15, q8 = (lane >> 4) * 8;

  int row = m0 + wv * 16 + n15;  // m = t*64 + b
  int t = row >> 6, b = row & 63;
  const float* arow = x + ((size_t)(b * TT + t)) * II + q8;

  const float* brow[4];
#pragma unroll
  for (int j = 0; j < 4; ++j) {
    int c = n0 + j * 16 + n15;
    brow[j] = ((c < SS) ? (Wm + (size_t)c * (II + DD)) : (Wv + (size_t)(c - SS) * (II + DD))) + q8;
  }
  f32x4 acc[4] = {};
#pragma unroll 4
  for (int k = 0; k < II; k += 32) {
    bf16x8 a = ld8f(arow + k);
#pragma unroll
    for (int j = 0; j < 4; ++j) acc[j] = MFMA16(a, ld8f(brow[j] + k), acc[j]);
  }
  int mb = m0 + wv * 16 + (lane >> 4) * 4;
#pragma unroll
  for (int j = 0; j < 4; ++j) {
    int c = n0 + j * 16 + n15;
    __bf16* dst = (c < SS) ? (xm + c) : (xv + (c - SS));
#pragma unroll
    for (int r = 0; r < 4; ++r) dst[(size_t)(mb + r) * SS] = (__bf16)acc[j][r];
  }
}

// ---------------------------------------------------------------------------
// k_scan v7 = R1-proven v4 structure + FIFO-aware scheduling:
//  * archive stores (h_all/z_all) issued AFTER the next step's hA loads —
//    behind the loads in the in-order vmcnt FIFO, so loads retire first and
//    the archives complete during the GEMM + z-wait (never in the drain, and
//    never ahead of critical-path loads like R2/R4's post-signal placement).
//  * posterior prefetches noise/xm/xv (t-dependent, h-independent) into
//    registers BEFORE the h-wait, removing their latency from the critical
//    section.
// Blocks 0..127: GRU, 8 h-cols. LDS: W_hh 48KB + W_ih 12KB, swizzled.
// Blocks 128..143: posterior, 16 z-cols. LDS: Wm/Wv h-part 64KB.
// ---------------------------------------------------------------------------
__global__ __launch_bounds__(256, 1) void k_scan(
    const float* __restrict__ Wih, const float* __restrict__ Whh,
    const float* __restrict__ bih, const float* __restrict__ bhh,
    const float* __restrict__ Wm, const float* __restrict__ bm,
    const float* __restrict__ Wv, const float* __restrict__ bv,
    const float* __restrict__ noise, char* __restrict__ ws, char* __restrict__ doutc) {
  __shared__ __bf16 smem[32768];  // 64 KB

  __bf16* hbL[2] = {(__bf16*)(ws + OFF_HB), (__bf16*)(ws + OFF_HB) + (size_t)BB * DD};
  __bf16* zb = (__bf16*)(ws + OFF_ZB);
  __bf16* z_all = (__bf16*)(ws + OFF_Z);
  __bf16* h_all = (__bf16*)doutc;
  const __bf16* xm = (const __bf16*)(doutc + DO_XM);
  const __bf16* xv = (const __bf16*)(doutc + DO_XV);
  int* hflag = (int*)(ws + OFF_CNT);
  int* zflag = hflag + 256;

  int blk = blockIdx.x, tid = threadIdx.x, lane = tid & 63, wv = tid >> 6;
  int n15 = lane & 15, q = lane >> 4, q8 = q * 8, q4 = q * 4;
  const int rb = wv * 16 + n15;  // A-fragment batch row

  if (blk < NGRU) {
    int c0 = blk * 8;
    int col8 = n15 & 7;
    int swq = (q + ((col8 >> 1) & 3)) & 3;  // bank swizzle (<=2-way, free)
    // ---- stage W_hh (3 gates x 8 cols x K=1024) into LDS [0,24576) elts
    for (int u = tid; u < 3072; u += 256) {
      int qq = u & 3, col = (u >> 2) & 7, kk = (u >> 5) & 31, g = u >> 10;
      int sq = (qq + ((col >> 1) & 3)) & 3;
      *(bf16x8*)(smem + ((((g * 32 + kk) * 8 + col) * 4) + sq) * 8) =
          ld8f(Whh + ((size_t)(g * DD + c0 + col)) * DD + kk * 32 + qq * 8);
    }
    // ---- stage W_ih (3 gates x 8 cols x K=256) into LDS [24576,30720) elts
    for (int u = tid; u < 768; u += 256) {
      int qq = u & 3, col = (u >> 2) & 7, kk = (u >> 5) & 7, g = u >> 8;
      int sq = (qq + ((col >> 1) & 3)) & 3;
      *(bf16x8*)(smem + 24576 + ((((g * 8 + kk) * 8 + col) * 4) + sq) * 8) =
          ld8f(Wih + ((size_t)(g * DD + c0 + col)) * SS + kk * 32 + qq * 8);
    }
    __syncthreads();

    int ccb = c0 + col8;  // output col (lanes n15>=8 duplicate, never stored)
    float brs = bih[ccb] + bhh[ccb];
    float bzs = bih[DD + ccb] + bhh[DD + ccb];
    float bin = bih[2 * DD + ccb];
    float bhn = bhh[2 * DD + ccb];
    f32x4 hcarry = {};  // fp32 h for rows mb..mb+3, col ccb — registers!
    int mb = wv * 16 + q4;

    for (int t = 0; t < TT; ++t) {
      f32x4 accr = {}, accz = {}, acchn = {}, accin = {};
      if (t > 0) {
        wait_flags(hflag, NGRU, t, true);  // h_{t-1} ready
        // batch-prefetch h_{t-1} A-fragments (plain dwordx4 after inv)
        const __bf16* hp = hbL[t & 1] + (size_t)rb * DD + q8;
        bf16x8 hA[32];
#pragma unroll
        for (int kk = 0; kk < 32; ++kk) hA[kk] = *(const bf16x8*)(hp + kk * 32);
        // archive h_{t-1} NOW: behind the hA loads in the vmcnt FIFO, so the
        // loads retire first and these NT stores complete during GEMM+z-wait.
        if (n15 < 8) {
          __bf16* hall_p = h_all + (size_t)(t - 1) * BB * DD;
#pragma unroll
          for (int r = 0; r < 4; ++r)
            __builtin_nontemporal_store((__bf16)hcarry[r], hall_p + (size_t)(mb + r) * DD + ccb);
        }
#pragma unroll
        for (int kk = 0; kk < 32; ++kk) {
          const __bf16* wb = smem + ((size_t)kk * 8 + col8) * 32 + swq * 8;
          accr = MFMA16(hA[kk], *(const bf16x8*)(wb), accr);
          accz = MFMA16(hA[kk], *(const bf16x8*)(wb + 8192), accz);
          acchn = MFMA16(hA[kk], *(const bf16x8*)(wb + 16384), acchn);
        }
        wait_flags(zflag, NPST, t, false);  // z_{t-1}; h-acquire already inv'd zb lines
        const __bf16* zp = zb + (size_t)rb * SS + q8;
        bf16x8 zA[8];
#pragma unroll
        for (int kk = 0; kk < 8; ++kk) zA[kk] = *(const bf16x8*)(zp + kk * 32);
#pragma unroll
        for (int kk = 0; kk < 8; ++kk) {
          const __bf16* wb = smem + 24576 + ((size_t)kk * 8 + col8) * 32 + swq * 8;
          accr = MFMA16(zA[kk], *(const bf16x8*)(wb), accr);
          accz = MFMA16(zA[kk], *(const bf16x8*)(wb + 2048), accz);
          accin = MFMA16(zA[kk], *(const bf16x8*)(wb + 4096), accin);
        }
      }
      __bf16* hw = hbL[(t + 1) & 1];
#pragma unroll
      for (int r = 0; r < 4; ++r) {
        int mm = mb + r;
        float rg = fsig(accr[r] + brs);
        float zg = fsig(accz[r] + bzs);
        float ng = ftanh(accin[r] + bin + rg * (acchn[r] + bhn));
        float hn = (1.f - zg) * ng + zg * hcarry[r];
        hcarry[r] = hn;
        if (n15 < 8) st2(hw + (size_t)mm * DD + ccb, hn);  // handoff (write-through)
      }
      // signal: drain handoff stores (archives already done), barrier, flag
      asm volatile("s_waitcnt vmcnt(0)" ::: "memory");
      __syncthreads();
      if (tid == 0)
        __hip_atomic_store(hflag + blk, t + 1, __ATOMIC_RELAXED, __HIP_MEMORY_SCOPE_AGENT);
    }
    // tail: archive h_{255}
    if (n15 < 8) {
      __bf16* hall_p = h_all + (size_t)(TT - 1) * BB * DD;
#pragma unroll
      for (int r = 0; r < 4; ++r)
        __builtin_nontemporal_store((__bf16)hcarry[r], hall_p + (size_t)(mb + r) * DD + ccb);
    }
  } else {
    int p = blk - NGRU, cp0 = p * 16;
    int swq = (q + ((n15 >> 1) & 3)) & 3;
    // ---- stage Wm/Wv h-part (2 x 16 cols x K=1024) into LDS (64 KB)
    for (int u = tid; u < 4096; u += 256) {
      int qq = u & 3, col = (u >> 2) & 15, kk = (u >> 6) & 31, mv = u >> 11;
      int sq = (qq + ((col >> 1) & 3)) & 3;
      const float* src = (mv ? Wv : Wm) + ((size_t)(cp0 + col)) * (II + DD) + II + kk * 32 + qq * 8;
      *(bf16x8*)(smem + ((((mv * 32 + kk) * 16 + col) * 4) + sq) * 8) = ld8f(src);
    }
    __syncthreads();

    int c2 = cp0 + n15;
    float bmv = bm[c2], bvv = bv[c2];
    int mb = wv * 16 + q4;
    f32x4 zsPrev = {};

    for (int t = 0; t < TT; ++t) {
      // prefetch t-dependent inputs (independent of h_t) BEFORE the wait
      float nzf[4], xmf[4], xvf[4];
#pragma unroll
      for (int r = 0; r < 4; ++r) {
        size_t gidx = ((size_t)t * BB + mb + r) * SS + c2;
        nzf[r] = noise[gidx];
        xmf[r] = (float)xm[gidx];
        xvf[r] = (float)xv[gidx];
      }
      wait_flags(hflag, NGRU, t + 1, true);  // h_t ready
      const __bf16* hp = hbL[(t + 1) & 1] + (size_t)rb * DD + q8;
      bf16x8 hA[32];
#pragma unroll
      for (int kk = 0; kk < 32; ++kk) hA[kk] = *(const bf16x8*)(hp + kk * 32);
      // archive z_{t-1} NOW (behind hA loads; completes during the GEMM)
      if (t > 0) {
#pragma unroll
        for (int r = 0; r < 4; ++r)
          __builtin_nontemporal_store((__bf16)zsPrev[r],
                                      z_all + ((size_t)(t - 1) * BB + mb + r) * SS + c2);
      }
      f32x4 am = {}, av = {};
#pragma unroll
      for (int kk = 0; kk < 32; ++kk) {
        const __bf16* wb = smem + ((size_t)kk * 16 + n15) * 32 + swq * 8;
        am = MFMA16(hA[kk], *(const bf16x8*)(wb), am);
        av = MFMA16(hA[kk], *(const bf16x8*)(wb + 16384), av);
      }
#pragma unroll
      for (int r = 0; r < 4; ++r) {
        int mm = mb + r;
        float mean = am[r] + bmv + xmf[r];
        float vr = av[r] + bvv + xvf[r];
        float sd = __expf(0.5f * vr);
        float zt = nzf[r] * sd + mean;
        zsPrev[r] = zt;
        st2(zb + (size_t)mm * SS + c2, zt);  // handoff
      }
      asm volatile("s_waitcnt vmcnt(0)" ::: "memory");
      __syncthreads();
      if (tid == 0)
        __hip_atomic_store(zflag + p, t + 1, __ATOMIC_RELAXED, __HIP_MEMORY_SCOPE_AGENT);
    }
    // tail: archive z_{255}
#pragma unroll
    for (int r = 0; r < 4; ++r)
      __builtin_nontemporal_store((__bf16)zsPrev[r],
                                  z_all + ((size_t)(TT - 1) * BB + mb + r) * SS + c2);
  }
}

// ---------------------------------------------------------------------------
// Decoder layer 0: elu([h_all | z_all] @ W0.T + b0) -> a0 (ws), K=1280.
// ---------------------------------------------------------------------------
__global__ __launch_bounds__(256, 2) void k_dec0(const char* __restrict__ doutc,
                                                 const char* __restrict__ ws,
                                                 const float* __restrict__ b0,
                                                 __bf16* __restrict__ C) {
  const __bf16* h_all = (const __bf16*)doutc;
  const __bf16* z_all = (const __bf16*)(ws + OFF_Z);
  const __bf16* W0b = (const __bf16*)(doutc + DO_WB0);
  int m0 = blockIdx.x * 128, n0 = blockIdx.y * 128;
  int tid = threadIdx.x, lane = tid & 63, w = tid >> 6;
  int wm = w >> 1, wn = w & 1;
  int n15 = lane & 15, q8 = (lane >> 4) * 8, q4 = (lane >> 4) * 4;

  const __bf16* hrow[4];
  const __bf16* zrow[4];
  const __bf16* brow[4];
#pragma unroll
  for (int i = 0; i < 4; ++i) {
    int row = m0 + wm * 64 + i * 16 + n15;  // m = b*256 + t
    int b = row >> 8, tq = row & 255;
    hrow[i] = h_all + ((size_t)tq * BB + b) * DD + q8;
    zrow[i] = z_all + ((size_t)tq * BB + b) * SS + q8;
  }
#pragma unroll
  for (int j = 0; j < 4; ++j)
    brow[j] = W0b + (size_t)(n0 + wn * 64 + j * 16 + n15) * (DD + SS) + q8;

  f32x4 acc[4][4] = {};
  for (int k = 0; k < DD + SS; k += 32) {
    bf16x8 af[4], bfv[4];
#pragma unroll
    for (int i = 0; i < 4; ++i)
      af[i] = (k < DD) ? *(const bf16x8*)(hrow[i] + k) : *(const bf16x8*)(zrow[i] + k - DD);
#pragma unroll
    for (int j = 0; j < 4; ++j) bfv[j] = *(const bf16x8*)(brow[j] + k);
#pragma unroll
    for (int i = 0; i < 4; ++i)
#pragma unroll
      for (int j = 0; j < 4; ++j) acc[i][j] = MFMA16(af[i], bfv[j], acc[i][j]);
  }
#pragma unroll
  for (int i = 0; i < 4; ++i) {
    int mr = m0 + wm * 64 + i * 16 + q4;
#pragma unroll
    for (int j = 0; j < 4; ++j) {
      int c = n0 + wn * 64 + j * 16 + n15;
      float bb = b0[c];
#pragma unroll
      for (int r = 0; r < 4; ++r) {
        float v = acc[i][j][r] + bb;
        v = v > 0.f ? v : (__expf(v) - 1.f);
        C[(size_t)(mr + r) * HH + c] = (__bf16)v;
      }
    }
  }
}

// ---------------------------------------------------------------------------
// Decoder mid layer: C = elu(A @ W.T + b), K = N = 1024; W pre-converted bf16.
// ---------------------------------------------------------------------------
__global__ __launch_bounds__(256, 2) void k_dec_mid(const __bf16* __restrict__ A,
                                                    const __bf16* __restrict__ W,
                                                    const float* __restrict__ bias,
                                                    __bf16* __restrict__ C) {
  int m0 = blockIdx.x * 128, n0 = blockIdx.y * 128;
  int tid = threadIdx.x, lane = tid & 63, w = tid >> 6;
  int wm = w >> 1, wn = w & 1;
  int n15 = lane & 15, q8 = (lane >> 4) * 8, q4 = (lane >> 4) * 4;

  const __bf16* arow[4];
  const __bf16* brow[4];
#pragma unroll
  for (int i = 0; i < 4; ++i) arow[i] = A + (size_t)(m0 + wm * 64 + i * 16 + n15) * DD + q8;
#pragma unroll
  for (int j = 0; j < 4; ++j) brow[j] = W + (size_t)(n0 + wn * 64 + j * 16 + n15) * DD + q8;

  f32x4 acc[4][4] = {};
  for (int k = 0; k < DD; k += 32) {
    bf16x8 af[4], bfv[4];
#pragma unroll
    for (int i = 0; i < 4; ++i) af[i] = *(const bf16x8*)(arow[i] + k);
#pragma unroll
    for (int j = 0; j < 4; ++j) bfv[j] = *(const bf16x8*)(brow[j] + k);
#pragma unroll
    for (int i = 0; i < 4; ++i)
#pragma unroll
      for (int j = 0; j < 4; ++j) acc[i][j] = MFMA16(af[i], bfv[j], acc[i][j]);
  }
#pragma unroll
  for (int i = 0; i < 4; ++i) {
    int mr = m0 + wm * 64 + i * 16 + q4;
#pragma unroll
    for (int j = 0; j < 4; ++j) {
      int c = n0 + wn * 64 + j * 16 + n15;
      float bb = bias[c];
#pragma unroll
      for (int r = 0; r < 4; ++r) {
        float v = acc[i][j][r] + bb;
        v = v > 0.f ? v : (__expf(v) - 1.f);
        C[(size_t)(mr + r) * HH + c] = (__bf16)v;
      }
    }
  }
}

// ---------------------------------------------------------------------------
// Decoder layer 3 + output assembly (fp32 outputs)
// ---------------------------------------------------------------------------
__global__ __launch_bounds__(256, 2) void k_dec3(const __bf16* __restrict__ A,
                                                 const float* __restrict__ W3,
                                                 const float* __restrict__ b3,
                                                 const float* __restrict__ x,
                                                 float* __restrict__ outd,
                                                 float* __restrict__ outh) {
  int m0 = blockIdx.x * 128, n0 = blockIdx.y * 128;
  int tid = threadIdx.x, lane = tid & 63, w = tid >> 6;
  int wm = w >> 1, wn = w & 1;
  int n15 = lane & 15, q8 = (lane >> 4) * 8, q4 = (lane >> 4) * 4;

  const __bf16* arow[4];
  const float* brow[4];
#pragma unroll
  for (int i = 0; i < 4; ++i) arow[i] = A + (size_t)(m0 + wm * 64 + i * 16 + n15) * HH + q8;
#pragma unroll
  for (int j = 0; j < 4; ++j) brow[j] = W3 + (size_t)(n0 + wn * 64 + j * 16 + n15) * HH + q8;

  f32x4 acc[4][4] = {};
  for (int k = 0; k < HH; k += 32) {
    bf16x8 af[4], bfv[4];
#pragma unroll
    for (int i = 0; i < 4; ++i) af[i] = *(const bf16x8*)(arow[i] + k);
#pragma unroll
    for (int j = 0; j < 4; ++j) bfv[j] = ld8f(brow[j] + k);
#pragma unroll
    for (int i = 0; i < 4; ++i)
#pragma unroll
      for (int j = 0; j < 4; ++j) acc[i][j] = MFMA16(af[i], bfv[j], acc[i][j]);
  }
#pragma unroll
  for (int i = 0; i < 4; ++i) {
    int mr = m0 + wm * 64 + i * 16 + q4;
#pragma unroll
    for (int j = 0; j < 4; ++j) {
      int c = n0 + wn * 64 + j * 16 + n15;
      float b3v = b3[c];
#pragma unroll
      for (int r = 0; r < 4; ++r) {
        int mm = mr + r;
        int b = mm >> 8, tq = mm & 255;
        float dv = acc[i][j][r] + b3v;
        if (tq < 255) {
          outd[((size_t)b * 255 + tq) * II + c] = dv;
          outh[((size_t)b * TT + tq + 1) * II + c] = x[((size_t)b * TT + tq) * II + c] + dv;
        }
        if (tq == 0) outh[((size_t)b * TT) * II + c] = x[((size_t)b * TT) * II + c];
      }
    }
  }
}

// ---------------------------------------------------------------------------
extern "C" void kernel_launch(void* const* d_in, const int* in_sizes, int n_in,
                              void* d_out, int out_size, void* d_ws, size_t ws_size,
                              hipStream_t stream) {
  const float* x = (const float*)d_in[0];
  const float* noise = (const float*)d_in[1];
  const float* W_ih = (const float*)d_in[2];
  const float* W_hh = (const float*)d_in[3];
  const float* b_ih = (const float*)d_in[4];
  const float* b_hh = (const float*)d_in[5];
  const float* Wm = (const float*)d_in[6];
  const float* bm = (const float*)d_in[7];
  const float* Wv = (const float*)d_in[8];
  const float* bv = (const float*)d_in[9];
  const float* dW0 = (const float*)d_in[10];
  const float* db0 = (const float*)d_in[11];
  const float* dW1 = (const float*)d_in[12];
  const float* db1 = (const float*)d_in[13];
  const float* dW2 = (const float*)d_in[14];
  const float* db2 = (const float*)d_in[15];
  const float* dW3 = (const float*)d_in[16];
  const float* db3 = (const float*)d_in[17];

  char* ws = (char*)d_ws;
  char* doutc = (char*)d_out;
  __bf16* a0 = (__bf16*)(ws + OFF_A);  // dec0 out
  __bf16* a1 = (__bf16*)doutc;         // dec1 out (over dead h_all)
  __bf16* a2 = (__bf16*)(ws + OFF_A);  // dec2 out (over dead a0)

  // 1) x-dependent posterior halves + flag zeroing + dec-weight bf16 staging
  k_xmv<<<dim3(256, 8), 256, 0, stream>>>(x, Wm, Wv, dW0, dW1, dW2, doutc, ws);

  // 2) persistent scan: 128 GRU + 16 posterior blocks, all weights in LDS
  k_scan<<<NGRU + NPST, 256, 0, stream>>>(W_ih, W_hh, b_ih, b_hh, Wm, bm, Wv, bv, noise, ws,
                                          doutc);

  // 3) decoder (W0/W1/W2 consumed as bf16 from d_out scratch; dead before dec3)
  k_dec0<<<dim3(128, 8), 256, 0, stream>>>(doutc, ws, db0, a0);
  k_dec_mid<<<dim3(128, 8), 256, 0, stream>>>(a0, (const __bf16*)(doutc + DO_WB1), db1, a1);
  k_dec_mid<<<dim3(128, 8), 256, 0, stream>>>(a1, (const __bf16*)(doutc + DO_WB2), db2, a2);
  k_dec3<<<dim3(128, 4), 256, 0, stream>>>(a2, dW3, db3, x, (float*)doutc,
                                           (float*)doutc + OUTD_ELEMS);
}

// Round 6
// 4252.805 us; speedup vs baseline: 1.3338x; 1.0134x over previous
//
#include <hip/hip_runtime.h>
#include <hip/hip_bf16.h>
#include <string.h>

typedef __bf16 bf16x8 __attribute__((ext_vector_type(8)));
typedef __bf16 bf16x4 __attribute__((ext_vector_type(4)));
typedef float f32x4 __attribute__((ext_vector_type(4)));

#define MFMA16(a, b, c) __builtin_amdgcn_mfma_f32_16x16x32_bf16((a), (b), (c), 0, 0, 0)

#define BB 64
#define TT 256
#define II 512
#define SS 256
#define DD 1024
#define HH 1024

// ---- ws layout (bytes); total ~42.3 MB (<= 43.02 MB proven) ----------------
#define OFF_A ((size_t)0)           // 32MB bf16 activation slot (a0, then a2)
#define OFF_Z ((size_t)33554432)    // 8MB bf16 z archive (T,B,S)
#define OFF_HB ((size_t)41943040)   // bf16 [2][64][1024] h handoff (8B WT stores)
#define OFF_ZB ((size_t)42205184)   // bf16 [64][256] z handoff
#define OFF_CNT ((size_t)42237952)  // int hflag[256] | zflag[256]

// ---- d_out (fp32, 66,977,792 B) scratch layout -----------------------------
#define DO_XM ((size_t)35651584)
#define DO_XV ((size_t)44040192)
#define DO_WB0 ((size_t)52428800)  // 1024*1280 bf16
#define DO_WB1 ((size_t)55050240)  // 1024*1024 bf16
#define DO_WB2 ((size_t)57147392)  // 1024*1024 bf16
#define OUTD_ELEMS 8355840  // 64*255*512

#define NGRU 128  // GRU blocks (8 h-cols each) — R1/R5-proven structure
#define NPST 16   // posterior blocks (16 z-cols each)

__device__ __forceinline__ float fsig(float x) { return 1.f / (1.f + __expf(-x)); }
__device__ __forceinline__ float ftanh(float x) {
  float ax = __builtin_fabsf(x);
  float e = __expf(-2.f * ax);
  float r = (1.f - e) / (1.f + e);
  return __builtin_copysignf(r, x);
}

__device__ __forceinline__ bf16x8 ld8f(const float* p) {
  float4 a = *(const float4*)p;
  float4 b = *(const float4*)(p + 4);
  bf16x8 r;
  r[0] = (__bf16)a.x; r[1] = (__bf16)a.y; r[2] = (__bf16)a.z; r[3] = (__bf16)a.w;
  r[4] = (__bf16)b.x; r[5] = (__bf16)b.y; r[6] = (__bf16)b.z; r[7] = (__bf16)b.w;
  return r;
}

// pack 4 fp32 -> 4 bf16 in a u64 (for one 8B write-through store)
__device__ __forceinline__ unsigned long long pack4(const f32x4 v) {
  union { __bf16 h[4]; unsigned long long u; } r;
  r.h[0] = (__bf16)v[0]; r.h[1] = (__bf16)v[1];
  r.h[2] = (__bf16)v[2]; r.h[3] = (__bf16)v[3];
  return r.u;
}

// ---- sync: per-block flag array; relaxed poll + one acquire, ONE barrier ---
// (acquire-inv before the barrier is sound: between any inv and the post-
//  barrier reads, L2 can only be refilled from L3 which holds fresh data.)
__device__ __forceinline__ void wait_flags(int* flags, int n, int target, bool acq) {
  if ((int)threadIdx.x < n) {
    while (__hip_atomic_load(flags + threadIdx.x, __ATOMIC_RELAXED, __HIP_MEMORY_SCOPE_AGENT) <
           target)
      __builtin_amdgcn_s_sleep(1);
  }
  if (acq && threadIdx.x == 0)
    (void)__hip_atomic_load(flags, __ATOMIC_ACQUIRE, __HIP_MEMORY_SCOPE_AGENT);  // one inv
  __syncthreads();
}
// 8-byte write-through (agent-relaxed) store
__device__ __forceinline__ void st8(void* p, unsigned long long u) {
  __hip_atomic_store((unsigned long long*)p, u, __ATOMIC_RELAXED, __HIP_MEMORY_SCOPE_AGENT);
}

// ---------------------------------------------------------------------------
// k_xmv: xm/xv = x @ Wm[:, :I].T, x @ Wv[:, :I].T -> bf16 into d_out scratch.
// Also zeroes the scan flags and converts dec weights W0/W1/W2 to bf16.
// ---------------------------------------------------------------------------
__global__ __launch_bounds__(256) void k_xmv(const float* __restrict__ x,
                                             const float* __restrict__ Wm,
                                             const float* __restrict__ Wv,
                                             const float* __restrict__ Wd0,
                                             const float* __restrict__ Wd1,
                                             const float* __restrict__ Wd2,
                                             char* __restrict__ doutc, char* __restrict__ ws) {
  if (blockIdx.x == 0 && blockIdx.y == 0) {
    int* cnt = (int*)(ws + OFF_CNT);
    cnt[threadIdx.x] = 0;
    cnt[threadIdx.x + 256] = 0;
  }
  {
    size_t lin = (size_t)blockIdx.y * 256 + blockIdx.x;  // 0..2047
    size_t g = (lin * 256 + threadIdx.x) * 8;            // 8 elems/thread
    if (g < 3407872) {
      const float* src;
      __bf16* dst;
      if (g < 1310720) {
        src = Wd0 + g;
        dst = (__bf16*)(doutc + DO_WB0) + g;
      } else if (g < 2359296) {
        src = Wd1 + (g - 1310720);
        dst = (__bf16*)(doutc + DO_WB1) + (g - 1310720);
      } else {
        src = Wd2 + (g - 2359296);
        dst = (__bf16*)(doutc + DO_WB2) + (g - 2359296);
      }
      *(bf16x8*)dst = ld8f(src);
    }
  }
  __bf16* xm = (__bf16*)(doutc + DO_XM);
  __bf16* xv = (__bf16*)(doutc + DO_XV);

  int m0 = blockIdx.x * 64, n0 = blockIdx.y * 64;
  int tid = threadIdx.x, lane = tid & 63, wv = tid >> 6;
  int n15 = lane & 15, q8 = (lane >> 4) * 8;

  int row = m0 + wv * 16 + n15;  // m = t*64 + b
  int t = row >> 6, b = row & 63;
  const float* arow = x + ((size_t)(b * TT + t)) * II + q8;

  const float* brow[4];
#pragma unroll
  for (int j = 0; j < 4; ++j) {
    int c = n0 + j * 16 + n15;
    brow[j] = ((c < SS) ? (Wm + (size_t)c * (II + DD)) : (Wv + (size_t)(c - SS) * (II + DD))) + q8;
  }
  f32x4 acc[4] = {};
#pragma unroll 4
  for (int k = 0; k < II; k += 32) {
    bf16x8 a = ld8f(arow + k);
#pragma unroll
    for (int j = 0; j < 4; ++j) acc[j] = MFMA16(a, ld8f(brow[j] + k), acc[j]);
  }
  int mb = m0 + wv * 16 + (lane >> 4) * 4;
#pragma unroll
  for (int j = 0; j < 4; ++j) {
    int c = n0 + j * 16 + n15;
    __bf16* dst = (c < SS) ? (xm + c) : (xv + (c - SS));
#pragma unroll
    for (int r = 0; r < 4; ++r) dst[(size_t)(mb + r) * SS] = (__bf16)acc[j][r];
  }
}

// ---------------------------------------------------------------------------
// k_scan v8 = R5 structure + operand-swapped MFMA output packing.
// mfma(W_frag, h_frag): A/B fragment layouts are identical (lane&15 index,
// lane>>4 k-chunk), so the same LDS reads and hA loads feed the swapped call;
// the C layout transposes to row=(lane>>4)*4+r -> OUTPUT COL, col=lane&15 ->
// batch row. Each lane now owns 4 CONSECUTIVE output cols of one batch row:
// handoff + archive stores become one aligned 8B store instead of 4 scattered
// 2B stores (4x fewer write-through L3 transactions in both drains).
// Archive stores stay behind the hA loads in the vmcnt FIFO (R5-proven).
// ---------------------------------------------------------------------------
__global__ __launch_bounds__(256, 1) void k_scan(
    const float* __restrict__ Wih, const float* __restrict__ Whh,
    const float* __restrict__ bih, const float* __restrict__ bhh,
    const float* __restrict__ Wm, const float* __restrict__ bm,
    const float* __restrict__ Wv, const float* __restrict__ bv,
    const float* __restrict__ noise, char* __restrict__ ws, char* __restrict__ doutc) {
  __shared__ __bf16 smem[32768];  // 64 KB

  __bf16* hbL[2] = {(__bf16*)(ws + OFF_HB), (__bf16*)(ws + OFF_HB) + (size_t)BB * DD};
  __bf16* zb = (__bf16*)(ws + OFF_ZB);
  __bf16* z_all = (__bf16*)(ws + OFF_Z);
  __bf16* h_all = (__bf16*)doutc;
  const __bf16* xm = (const __bf16*)(doutc + DO_XM);
  const __bf16* xv = (const __bf16*)(doutc + DO_XV);
  int* hflag = (int*)(ws + OFF_CNT);
  int* zflag = hflag + 256;

  int blk = blockIdx.x, tid = threadIdx.x, lane = tid & 63, wv = tid >> 6;
  int n15 = lane & 15, q = lane >> 4, q8 = q * 8;
  const int rb = wv * 16 + n15;  // batch row this lane owns (B-operand col)

  if (blk < NGRU) {
    int c0 = blk * 8;
    int col8 = n15 & 7;
    int swq = (q + ((col8 >> 1) & 3)) & 3;  // bank swizzle (<=2-way, free)
    // ---- stage W_hh (3 gates x 8 cols x K=1024) into LDS [0,24576) elts
    for (int u = tid; u < 3072; u += 256) {
      int qq = u & 3, col = (u >> 2) & 7, kk = (u >> 5) & 31, g = u >> 10;
      int sq = (qq + ((col >> 1) & 3)) & 3;
      *(bf16x8*)(smem + ((((g * 32 + kk) * 8 + col) * 4) + sq) * 8) =
          ld8f(Whh + ((size_t)(g * DD + c0 + col)) * DD + kk * 32 + qq * 8);
    }
    // ---- stage W_ih (3 gates x 8 cols x K=256) into LDS [24576,30720) elts
    for (int u = tid; u < 768; u += 256) {
      int qq = u & 3, col = (u >> 2) & 7, kk = (u >> 5) & 7, g = u >> 8;
      int sq = (qq + ((col >> 1) & 3)) & 3;
      *(bf16x8*)(smem + 24576 + ((((g * 8 + kk) * 8 + col) * 4) + sq) * 8) =
          ld8f(Wih + ((size_t)(g * DD + c0 + col)) * SS + kk * 32 + qq * 8);
    }
    __syncthreads();

    // this lane's 4 output cols: c0 + q*4 .. +3, valid for q<2 (q>=2 duplicates)
    int colw = c0 + (q & 1) * 4;
    f32x4 brs = *(const f32x4*)(bih + colw);
    brs += *(const f32x4*)(bhh + colw);
    f32x4 bzs = *(const f32x4*)(bih + DD + colw);
    bzs += *(const f32x4*)(bhh + DD + colw);
    f32x4 bin4 = *(const f32x4*)(bih + 2 * DD + colw);
    f32x4 bhn4 = *(const f32x4*)(bhh + 2 * DD + colw);
    f32x4 hcarry = {};  // h[rb][colw..colw+3] in fp32 registers

    for (int t = 0; t < TT; ++t) {
      f32x4 accr = {}, accz = {}, acchn = {}, accin = {};
      if (t > 0) {
        wait_flags(hflag, NGRU, t, true);  // h_{t-1} ready
        const __bf16* hp = hbL[t & 1] + (size_t)rb * DD + q8;
        bf16x8 hA[32];
#pragma unroll
        for (int kk = 0; kk < 32; ++kk) hA[kk] = *(const bf16x8*)(hp + kk * 32);
        // archive h_{t-1}: behind hA loads in FIFO; completes during GEMM+z-wait
        if (q < 2)
          __builtin_nontemporal_store(
              pack4(hcarry),
              (unsigned long long*)(h_all + (size_t)(t - 1) * BB * DD + (size_t)rb * DD + colw));
#pragma unroll
        for (int kk = 0; kk < 32; ++kk) {
          const __bf16* wb = smem + ((size_t)kk * 8 + col8) * 32 + swq * 8;
          accr = MFMA16(*(const bf16x8*)(wb), hA[kk], accr);
          accz = MFMA16(*(const bf16x8*)(wb + 8192), hA[kk], accz);
          acchn = MFMA16(*(const bf16x8*)(wb + 16384), hA[kk], acchn);
        }
        wait_flags(zflag, NPST, t, false);  // z_{t-1}; h-acquire already inv'd zb
        const __bf16* zp = zb + (size_t)rb * SS + q8;
        bf16x8 zA[8];
#pragma unroll
        for (int kk = 0; kk < 8; ++kk) zA[kk] = *(const bf16x8*)(zp + kk * 32);
#pragma unroll
        for (int kk = 0; kk < 8; ++kk) {
          const __bf16* wb = smem + 24576 + ((size_t)kk * 8 + col8) * 32 + swq * 8;
          accr = MFMA16(*(const bf16x8*)(wb), zA[kk], accr);
          accz = MFMA16(*(const bf16x8*)(wb + 2048), zA[kk], accz);
          accin = MFMA16(*(const bf16x8*)(wb + 4096), zA[kk], accin);
        }
      }
      __bf16* hw = hbL[(t + 1) & 1];
#pragma unroll
      for (int r = 0; r < 4; ++r) {
        float rg = fsig(accr[r] + brs[r]);
        float zg = fsig(accz[r] + bzs[r]);
        float ng = ftanh(accin[r] + bin4[r] + rg * (acchn[r] + bhn4[r]));
        hcarry[r] = (1.f - zg) * ng + zg * hcarry[r];
      }
      if (q < 2) st8(hw + (size_t)rb * DD + colw, pack4(hcarry));  // one 8B WT store
      // signal: drain handoff stores, barrier, one uncontended flag store
      asm volatile("s_waitcnt vmcnt(0)" ::: "memory");
      __syncthreads();
      if (tid == 0)
        __hip_atomic_store(hflag + blk, t + 1, __ATOMIC_RELAXED, __HIP_MEMORY_SCOPE_AGENT);
    }
    // tail: archive h_{255}
    if (q < 2)
      __builtin_nontemporal_store(
          pack4(hcarry),
          (unsigned long long*)(h_all + (size_t)(TT - 1) * BB * DD + (size_t)rb * DD + colw));
  } else {
    int p = blk - NGRU, cp0 = p * 16;
    int swq = (q + ((n15 >> 1) & 3)) & 3;
    // ---- stage Wm/Wv h-part (2 x 16 cols x K=1024) into LDS (64 KB)
    for (int u = tid; u < 4096; u += 256) {
      int qq = u & 3, col = (u >> 2) & 15, kk = (u >> 6) & 31, mv = u >> 11;
      int sq = (qq + ((col >> 1) & 3)) & 3;
      const float* src = (mv ? Wv : Wm) + ((size_t)(cp0 + col)) * (II + DD) + II + kk * 32 + qq * 8;
      *(bf16x8*)(smem + ((((mv * 32 + kk) * 16 + col) * 4) + sq) * 8) = ld8f(src);
    }
    __syncthreads();

    int c4 = cp0 + q * 4;  // this lane's 4 z-cols (all valid)
    f32x4 bmv = *(const f32x4*)(bm + c4);
    f32x4 bvv = *(const f32x4*)(bv + c4);
    f32x4 zsPrev = {};

    for (int t = 0; t < TT; ++t) {
      // prefetch t-dependent inputs (independent of h_t) BEFORE the wait
      size_t base = ((size_t)t * BB + rb) * SS + c4;
      f32x4 nz = *(const f32x4*)(noise + base);
      bf16x4 xm4 = *(const bf16x4*)(xm + base);
      bf16x4 xv4 = *(const bf16x4*)(xv + base);

      wait_flags(hflag, NGRU, t + 1, true);  // h_t ready
      const __bf16* hp = hbL[(t + 1) & 1] + (size_t)rb * DD + q8;
      bf16x8 hA[32];
#pragma unroll
      for (int kk = 0; kk < 32; ++kk) hA[kk] = *(const bf16x8*)(hp + kk * 32);
      // archive z_{t-1}: behind hA loads in FIFO; completes during the GEMM
      if (t > 0)
        __builtin_nontemporal_store(
            pack4(zsPrev),
            (unsigned long long*)(z_all + ((size_t)(t - 1) * BB + rb) * SS + c4));
      f32x4 am = {}, av = {};
#pragma unroll
      for (int kk = 0; kk < 32; ++kk) {
        const __bf16* wb = smem + ((size_t)kk * 16 + n15) * 32 + swq * 8;
        am = MFMA16(*(const bf16x8*)(wb), hA[kk], am);
        av = MFMA16(*(const bf16x8*)(wb + 16384), hA[kk], av);
      }
#pragma unroll
      for (int r = 0; r < 4; ++r) {
        float mean = am[r] + bmv[r] + (float)xm4[r];
        float vr = av[r] + bvv[r] + (float)xv4[r];
        float sd = __expf(0.5f * vr);
        zsPrev[r] = nz[r] * sd + mean;
      }
      st8(zb + (size_t)rb * SS + c4, pack4(zsPrev));  // one 8B WT store
      asm volatile("s_waitcnt vmcnt(0)" ::: "memory");
      __syncthreads();
      if (tid == 0)
        __hip_atomic_store(zflag + p, t + 1, __ATOMIC_RELAXED, __HIP_MEMORY_SCOPE_AGENT);
    }
    // tail: archive z_{255}
    __builtin_nontemporal_store(
        pack4(zsPrev), (unsigned long long*)(z_all + ((size_t)(TT - 1) * BB + rb) * SS + c4));
  }
}

// ---------------------------------------------------------------------------
// Decoder layer 0: elu([h_all | z_all] @ W0.T + b0) -> a0 (ws), K=1280.
// ---------------------------------------------------------------------------
__global__ __launch_bounds__(256, 2) void k_dec0(const char* __restrict__ doutc,
                                                 const char* __restrict__ ws,
                                                 const float* __restrict__ b0,
                                                 __bf16* __restrict__ C) {
  const __bf16* h_all = (const __bf16*)doutc;
  const __bf16* z_all = (const __bf16*)(ws + OFF_Z);
  const __bf16* W0b = (const __bf16*)(doutc + DO_WB0);
  int m0 = blockIdx.x * 128, n0 = blockIdx.y * 128;
  int tid = threadIdx.x, lane = tid & 63, w = tid >> 6;
  int wm = w >> 1, wn = w & 1;
  int n15 = lane & 15, q8 = (lane >> 4) * 8, q4 = (lane >> 4) * 4;

  const __bf16* hrow[4];
  const __bf16* zrow[4];
  const __bf16* brow[4];
#pragma unroll
  for (int i = 0; i < 4; ++i) {
    int row = m0 + wm * 64 + i * 16 + n15;  // m = b*256 + t
    int b = row >> 8, tq = row & 255;
    hrow[i] = h_all + ((size_t)tq * BB + b) * DD + q8;
    zrow[i] = z_all + ((size_t)tq * BB + b) * SS + q8;
  }
#pragma unroll
  for (int j = 0; j < 4; ++j)
    brow[j] = W0b + (size_t)(n0 + wn * 64 + j * 16 + n15) * (DD + SS) + q8;

  f32x4 acc[4][4] = {};
  for (int k = 0; k < DD + SS; k += 32) {
    bf16x8 af[4], bfv[4];
#pragma unroll
    for (int i = 0; i < 4; ++i)
      af[i] = (k < DD) ? *(const bf16x8*)(hrow[i] + k) : *(const bf16x8*)(zrow[i] + k - DD);
#pragma unroll
    for (int j = 0; j < 4; ++j) bfv[j] = *(const bf16x8*)(brow[j] + k);
#pragma unroll
    for (int i = 0; i < 4; ++i)
#pragma unroll
      for (int j = 0; j < 4; ++j) acc[i][j] = MFMA16(af[i], bfv[j], acc[i][j]);
  }
#pragma unroll
  for (int i = 0; i < 4; ++i) {
    int mr = m0 + wm * 64 + i * 16 + q4;
#pragma unroll
    for (int j = 0; j < 4; ++j) {
      int c = n0 + wn * 64 + j * 16 + n15;
      float bb = b0[c];
#pragma unroll
      for (int r = 0; r < 4; ++r) {
        float v = acc[i][j][r] + bb;
        v = v > 0.f ? v : (__expf(v) - 1.f);
        C[(size_t)(mr + r) * HH + c] = (__bf16)v;
      }
    }
  }
}

// ---------------------------------------------------------------------------
// Decoder mid layer: C = elu(A @ W.T + b), K = N = 1024; W pre-converted bf16.
// ---------------------------------------------------------------------------
__global__ __launch_bounds__(256, 2) void k_dec_mid(const __bf16* __restrict__ A,
                                                    const __bf16* __restrict__ W,
                                                    const float* __restrict__ bias,
                                                    __bf16* __restrict__ C) {
  int m0 = blockIdx.x * 128, n0 = blockIdx.y * 128;
  int tid = threadIdx.x, lane = tid & 63, w = tid >> 6;
  int wm = w >> 1, wn = w & 1;
  int n15 = lane & 15, q8 = (lane >> 4) * 8, q4 = (lane >> 4) * 4;

  const __bf16* arow[4];
  const __bf16* brow[4];
#pragma unroll
  for (int i = 0; i < 4; ++i) arow[i] = A + (size_t)(m0 + wm * 64 + i * 16 + n15) * DD + q8;
#pragma unroll
  for (int j = 0; j < 4; ++j) brow[j] = W + (size_t)(n0 + wn * 64 + j * 16 + n15) * DD + q8;

  f32x4 acc[4][4] = {};
  for (int k = 0; k < DD; k += 32) {
    bf16x8 af[4], bfv[4];
#pragma unroll
    for (int i = 0; i < 4; ++i) af[i] = *(const bf16x8*)(arow[i] + k);
#pragma unroll
    for (int j = 0; j < 4; ++j) bfv[j] = *(const bf16x8*)(brow[j] + k);
#pragma unroll
    for (int i = 0; i < 4; ++i)
#pragma unroll
      for (int j = 0; j < 4; ++j) acc[i][j] = MFMA16(af[i], bfv[j], acc[i][j]);
  }
#pragma unroll
  for (int i = 0; i < 4; ++i) {
    int mr = m0 + wm * 64 + i * 16 + q4;
#pragma unroll
    for (int j = 0; j < 4; ++j) {
      int c = n0 + wn * 64 + j * 16 + n15;
      float bb = bias[c];
#pragma unroll
      for (int r = 0; r < 4; ++r) {
        float v = acc[i][j][r] + bb;
        v = v > 0.f ? v : (__expf(v) - 1.f);
        C[(size_t)(mr + r) * HH + c] = (__bf16)v;
      }
    }
  }
}

// ---------------------------------------------------------------------------
// Decoder layer 3 + output assembly (fp32 outputs)
// ---------------------------------------------------------------------------
__global__ __launch_bounds__(256, 2) void k_dec3(const __bf16* __restrict__ A,
                                                 const float* __restrict__ W3,
                                                 const float* __restrict__ b3,
                                                 const float* __restrict__ x,
                                                 float* __restrict__ outd,
                                                 float* __restrict__ outh) {
  int m0 = blockIdx.x * 128, n0 = blockIdx.y * 128;
  int tid = threadIdx.x, lane = tid & 63, w = tid >> 6;
  int wm = w >> 1, wn = w & 1;
  int n15 = lane & 15, q8 = (lane >> 4) * 8, q4 = (lane >> 4) * 4;

  const __bf16* arow[4];
  const float* brow[4];
#pragma unroll
  for (int i = 0; i < 4; ++i) arow[i] = A + (size_t)(m0 + wm * 64 + i * 16 + n15) * HH + q8;
#pragma unroll
  for (int j = 0; j < 4; ++j) brow[j] = W3 + (size_t)(n0 + wn * 64 + j * 16 + n15) * HH + q8;

  f32x4 acc[4][4] = {};
  for (int k = 0; k < HH; k += 32) {
    bf16x8 af[4], bfv[4];
#pragma unroll
    for (int i = 0; i < 4; ++i) af[i] = *(const bf16x8*)(arow[i] + k);
#pragma unroll
    for (int j = 0; j < 4; ++j) bfv[j] = ld8f(brow[j] + k);
#pragma unroll
    for (int i = 0; i < 4; ++i)
#pragma unroll
      for (int j = 0; j < 4; ++j) acc[i][j] = MFMA16(af[i], bfv[j], acc[i][j]);
  }
#pragma unroll
  for (int i = 0; i < 4; ++i) {
    int mr = m0 + wm * 64 + i * 16 + q4;
#pragma unroll
    for (int j = 0; j < 4; ++j) {
      int c = n0 + wn * 64 + j * 16 + n15;
      float b3v = b3[c];
#pragma unroll
      for (int r = 0; r < 4; ++r) {
        int mm = mr + r;
        int b = mm >> 8, tq = mm & 255;
        float dv = acc[i][j][r] + b3v;
        if (tq < 255) {
          outd[((size_t)b * 255 + tq) * II + c] = dv;
          outh[((size_t)b * TT + tq + 1) * II + c] = x[((size_t)b * TT + tq) * II + c] + dv;
        }
        if (tq == 0) outh[((size_t)b * TT) * II + c] = x[((size_t)b * TT) * II + c];
      }
    }
  }
}

// ---------------------------------------------------------------------------
extern "C" void kernel_launch(void* const* d_in, const int* in_sizes, int n_in,
                              void* d_out, int out_size, void* d_ws, size_t ws_size,
                              hipStream_t stream) {
  const float* x = (const float*)d_in[0];
  const float* noise = (const float*)d_in[1];
  const float* W_ih = (const float*)d_in[2];
  const float* W_hh = (const float*)d_in[3];
  const float* b_ih = (const float*)d_in[4];
  const float* b_hh = (const float*)d_in[5];
  const float* Wm = (const float*)d_in[6];
  const float* bm = (const float*)d_in[7];
  const float* Wv = (const float*)d_in[8];
  const float* bv = (const float*)d_in[9];
  const float* dW0 = (const float*)d_in[10];
  const float* db0 = (const float*)d_in[11];
  const float* dW1 = (const float*)d_in[12];
  const float* db1 = (const float*)d_in[13];
  const float* dW2 = (const float*)d_in[14];
  const float* db2 = (const float*)d_in[15];
  const float* dW3 = (const float*)d_in[16];
  const float* db3 = (const float*)d_in[17];

  char* ws = (char*)d_ws;
  char* doutc = (char*)d_out;
  __bf16* a0 = (__bf16*)(ws + OFF_A);  // dec0 out
  __bf16* a1 = (__bf16*)doutc;         // dec1 out (over dead h_all)
  __bf16* a2 = (__bf16*)(ws + OFF_A);  // dec2 out (over dead a0)

  // 1) x-dependent posterior halves + flag zeroing + dec-weight bf16 staging
  k_xmv<<<dim3(256, 8), 256, 0, stream>>>(x, Wm, Wv, dW0, dW1, dW2, doutc, ws);

  // 2) persistent scan: 128 GRU + 16 posterior blocks, all weights in LDS
  k_scan<<<NGRU + NPST, 256, 0, stream>>>(W_ih, W_hh, b_ih, b_hh, Wm, bm, Wv, bv, noise, ws,
                                          doutc);

  // 3) decoder (W0/W1/W2 consumed as bf16 from d_out scratch; dead before dec3)
  k_dec0<<<dim3(128, 8), 256, 0, stream>>>(doutc, ws, db0, a0);
  k_dec_mid<<<dim3(128, 8), 256, 0, stream>>>(a0, (const __bf16*)(doutc + DO_WB1), db1, a1);
  k_dec_mid<<<dim3(128, 8), 256, 0, stream>>>(a1, (const __bf16*)(doutc + DO_WB2), db2, a2);
  k_dec3<<<dim3(128, 4), 256, 0, stream>>>(a2, dW3, db3, x, (float*)doutc,
                                           (float*)doutc + OUTD_ELEMS);
}

// Round 7
// 4143.796 us; speedup vs baseline: 1.3689x; 1.0263x over previous
//
#include <hip/hip_runtime.h>
#include <hip/hip_bf16.h>
#include <string.h>

typedef __bf16 bf16x8 __attribute__((ext_vector_type(8)));
typedef __bf16 bf16x4 __attribute__((ext_vector_type(4)));
typedef float f32x4 __attribute__((ext_vector_type(4)));

#define MFMA16(a, b, c) __builtin_amdgcn_mfma_f32_16x16x32_bf16((a), (b), (c), 0, 0, 0)

#define BB 64
#define TT 256
#define II 512
#define SS 256
#define DD 1024
#define HH 1024

// ---- ws layout (bytes); total ~42.3 MB (<= 43.02 MB proven) ----------------
#define OFF_A ((size_t)0)           // 32MB bf16 activation slot (a0, then a2)
#define OFF_Z ((size_t)33554432)    // 8MB bf16 z archive; after dec0: W3 bf16 copy
#define OFF_HB ((size_t)41943040)   // bf16 [2][64][1024] h handoff (8B WT stores)
#define OFF_ZB ((size_t)42205184)   // bf16 [64][256] z handoff
#define OFF_CNT ((size_t)42237952)  // int hflag[256] | zflag[256]

// ---- d_out (fp32, 66,977,792 B) scratch layout -----------------------------
#define DO_XM ((size_t)35651584)
#define DO_XV ((size_t)44040192)
#define DO_WB0 ((size_t)52428800)  // 1024*1280 bf16
#define DO_WB1 ((size_t)55050240)  // 1024*1024 bf16
#define DO_WB2 ((size_t)57147392)  // 1024*1024 bf16
#define OUTD_ELEMS 8355840  // 64*255*512

#define NGRU 128  // GRU blocks (8 h-cols each) — R1/R5/R6-proven structure
#define NPST 16   // posterior blocks (16 z-cols each)

__device__ __forceinline__ float fsig(float x) { return 1.f / (1.f + __expf(-x)); }
__device__ __forceinline__ float ftanh(float x) {
  float ax = __builtin_fabsf(x);
  float e = __expf(-2.f * ax);
  float r = (1.f - e) / (1.f + e);
  return __builtin_copysignf(r, x);
}

__device__ __forceinline__ bf16x8 ld8f(const float* p) {
  float4 a = *(const float4*)p;
  float4 b = *(const float4*)(p + 4);
  bf16x8 r;
  r[0] = (__bf16)a.x; r[1] = (__bf16)a.y; r[2] = (__bf16)a.z; r[3] = (__bf16)a.w;
  r[4] = (__bf16)b.x; r[5] = (__bf16)b.y; r[6] = (__bf16)b.z; r[7] = (__bf16)b.w;
  return r;
}

// pack 4 fp32 -> 4 bf16 in a u64 (one 8B store)
__device__ __forceinline__ unsigned long long pack4(const f32x4 v) {
  union { __bf16 h[4]; unsigned long long u; } r;
  r.h[0] = (__bf16)v[0]; r.h[1] = (__bf16)v[1];
  r.h[2] = (__bf16)v[2]; r.h[3] = (__bf16)v[3];
  return r.u;
}

// ---- sync v9: single-wave backoff polling ----------------------------------
// Only wave 0 polls (64 lanes x up to 2 flags); waves 1..3 park at the
// barrier (issue no L3 traffic). s_sleep(8) (~0.2us) between poll rounds cuts
// the agent-atomic request rate ~30x vs all-thread tight polling — the theory
// is that poll-request pressure on L3 ports was inflating flag-store
// visibility + broadcast-load latency (the unexplained ~4us/step).
__device__ __forceinline__ void wait_flags(int* flags, int n, int target, bool acq) {
  int tid = threadIdx.x;
  if (tid < 64) {
    int i1 = tid + 64;
    for (;;) {
      int v0 = __hip_atomic_load(flags + (tid < n ? tid : 0), __ATOMIC_RELAXED,
                                 __HIP_MEMORY_SCOPE_AGENT);
      int v1 = (i1 < n) ? __hip_atomic_load(flags + i1, __ATOMIC_RELAXED,
                                            __HIP_MEMORY_SCOPE_AGENT)
                        : target;
      if (v0 >= target && v1 >= target) break;
      __builtin_amdgcn_s_sleep(8);
    }
  }
  if (acq && tid == 0)
    (void)__hip_atomic_load(flags, __ATOMIC_ACQUIRE, __HIP_MEMORY_SCOPE_AGENT);  // one inv
  __syncthreads();
}
// 8-byte write-through (agent-relaxed) store
__device__ __forceinline__ void st8(void* p, unsigned long long u) {
  __hip_atomic_store((unsigned long long*)p, u, __ATOMIC_RELAXED, __HIP_MEMORY_SCOPE_AGENT);
}

// ---------------------------------------------------------------------------
// k_xmv: xm/xv = x @ Wm[:, :I].T, x @ Wv[:, :I].T -> bf16 into d_out scratch.
// Also zeroes the scan flags and converts dec weights W0/W1/W2 to bf16.
// ---------------------------------------------------------------------------
__global__ __launch_bounds__(256) void k_xmv(const float* __restrict__ x,
                                             const float* __restrict__ Wm,
                                             const float* __restrict__ Wv,
                                             const float* __restrict__ Wd0,
                                             const float* __restrict__ Wd1,
                                             const float* __restrict__ Wd2,
                                             char* __restrict__ doutc, char* __restrict__ ws) {
  if (blockIdx.x == 0 && blockIdx.y == 0) {
    int* cnt = (int*)(ws + OFF_CNT);
    cnt[threadIdx.x] = 0;
    cnt[threadIdx.x + 256] = 0;
  }
  {
    size_t lin = (size_t)blockIdx.y * 256 + blockIdx.x;  // 0..2047
    size_t g = (lin * 256 + threadIdx.x) * 8;            // 8 elems/thread
    if (g < 3407872) {
      const float* src;
      __bf16* dst;
      if (g < 1310720) {
        src = Wd0 + g;
        dst = (__bf16*)(doutc + DO_WB0) + g;
      } else if (g < 2359296) {
        src = Wd1 + (g - 1310720);
        dst = (__bf16*)(doutc + DO_WB1) + (g - 1310720);
      } else {
        src = Wd2 + (g - 2359296);
        dst = (__bf16*)(doutc + DO_WB2) + (g - 2359296);
      }
      *(bf16x8*)dst = ld8f(src);
    }
  }
  __bf16* xm = (__bf16*)(doutc + DO_XM);
  __bf16* xv = (__bf16*)(doutc + DO_XV);

  int m0 = blockIdx.x * 64, n0 = blockIdx.y * 64;
  int tid = threadIdx.x, lane = tid & 63, wv = tid >> 6;
  int n15 = lane & 15, q8 = (lane >> 4) * 8;

  int row = m0 + wv * 16 + n15;  // m = t*64 + b
  int t = row >> 6, b = row & 63;
  const float* arow = x + ((size_t)(b * TT + t)) * II + q8;

  const float* brow[4];
#pragma unroll
  for (int j = 0; j < 4; ++j) {
    int c = n0 + j * 16 + n15;
    brow[j] = ((c < SS) ? (Wm + (size_t)c * (II + DD)) : (Wv + (size_t)(c - SS) * (II + DD))) + q8;
  }
  f32x4 acc[4] = {};
#pragma unroll 4
  for (int k = 0; k < II; k += 32) {
    bf16x8 a = ld8f(arow + k);
#pragma unroll
    for (int j = 0; j < 4; ++j) acc[j] = MFMA16(a, ld8f(brow[j] + k), acc[j]);
  }
  int mb = m0 + wv * 16 + (lane >> 4) * 4;
#pragma unroll
  for (int j = 0; j < 4; ++j) {
    int c = n0 + j * 16 + n15;
    __bf16* dst = (c < SS) ? (xm + c) : (xv + (c - SS));
#pragma unroll
    for (int r = 0; r < 4; ++r) dst[(size_t)(mb + r) * SS] = (__bf16)acc[j][r];
  }
}

// ---------------------------------------------------------------------------
// k_scan v9 = R6 structure (operand-swapped MFMA, 8B packed handoff/archive,
// FIFO-scheduled archives) + single-wave backoff polling.
// ---------------------------------------------------------------------------
__global__ __launch_bounds__(256, 1) void k_scan(
    const float* __restrict__ Wih, const float* __restrict__ Whh,
    const float* __restrict__ bih, const float* __restrict__ bhh,
    const float* __restrict__ Wm, const float* __restrict__ bm,
    const float* __restrict__ Wv, const float* __restrict__ bv,
    const float* __restrict__ noise, char* __restrict__ ws, char* __restrict__ doutc) {
  __shared__ __bf16 smem[32768];  // 64 KB

  __bf16* hbL[2] = {(__bf16*)(ws + OFF_HB), (__bf16*)(ws + OFF_HB) + (size_t)BB * DD};
  __bf16* zb = (__bf16*)(ws + OFF_ZB);
  __bf16* z_all = (__bf16*)(ws + OFF_Z);
  __bf16* h_all = (__bf16*)doutc;
  const __bf16* xm = (const __bf16*)(doutc + DO_XM);
  const __bf16* xv = (const __bf16*)(doutc + DO_XV);
  int* hflag = (int*)(ws + OFF_CNT);
  int* zflag = hflag + 256;

  int blk = blockIdx.x, tid = threadIdx.x, lane = tid & 63, wv = tid >> 6;
  int n15 = lane & 15, q = lane >> 4, q8 = q * 8;
  const int rb = wv * 16 + n15;  // batch row this lane owns (B-operand col)

  if (blk < NGRU) {
    int c0 = blk * 8;
    int col8 = n15 & 7;
    int swq = (q + ((col8 >> 1) & 3)) & 3;  // bank swizzle (<=2-way, free)
    // ---- stage W_hh (3 gates x 8 cols x K=1024) into LDS [0,24576) elts
    for (int u = tid; u < 3072; u += 256) {
      int qq = u & 3, col = (u >> 2) & 7, kk = (u >> 5) & 31, g = u >> 10;
      int sq = (qq + ((col >> 1) & 3)) & 3;
      *(bf16x8*)(smem + ((((g * 32 + kk) * 8 + col) * 4) + sq) * 8) =
          ld8f(Whh + ((size_t)(g * DD + c0 + col)) * DD + kk * 32 + qq * 8);
    }
    // ---- stage W_ih (3 gates x 8 cols x K=256) into LDS [24576,30720) elts
    for (int u = tid; u < 768; u += 256) {
      int qq = u & 3, col = (u >> 2) & 7, kk = (u >> 5) & 7, g = u >> 8;
      int sq = (qq + ((col >> 1) & 3)) & 3;
      *(bf16x8*)(smem + 24576 + ((((g * 8 + kk) * 8 + col) * 4) + sq) * 8) =
          ld8f(Wih + ((size_t)(g * DD + c0 + col)) * SS + kk * 32 + qq * 8);
    }
    __syncthreads();

    // this lane's 4 output cols: c0 + (q&1)*4 .. +3 (q>=2 duplicates, unstored)
    int colw = c0 + (q & 1) * 4;
    f32x4 brs = *(const f32x4*)(bih + colw);
    brs += *(const f32x4*)(bhh + colw);
    f32x4 bzs = *(const f32x4*)(bih + DD + colw);
    bzs += *(const f32x4*)(bhh + DD + colw);
    f32x4 bin4 = *(const f32x4*)(bih + 2 * DD + colw);
    f32x4 bhn4 = *(const f32x4*)(bhh + 2 * DD + colw);
    f32x4 hcarry = {};  // h[rb][colw..colw+3] in fp32 registers

    for (int t = 0; t < TT; ++t) {
      f32x4 accr = {}, accz = {}, acchn = {}, accin = {};
      if (t > 0) {
        wait_flags(hflag, NGRU, t, true);  // h_{t-1} ready
        const __bf16* hp = hbL[t & 1] + (size_t)rb * DD + q8;
        bf16x8 hA[32];
#pragma unroll
        for (int kk = 0; kk < 32; ++kk) hA[kk] = *(const bf16x8*)(hp + kk * 32);
        // archive h_{t-1}: behind hA loads in FIFO; completes during GEMM+z-wait
        if (q < 2)
          __builtin_nontemporal_store(
              pack4(hcarry),
              (unsigned long long*)(h_all + (size_t)(t - 1) * BB * DD + (size_t)rb * DD + colw));
#pragma unroll
        for (int kk = 0; kk < 32; ++kk) {
          const __bf16* wb = smem + ((size_t)kk * 8 + col8) * 32 + swq * 8;
          accr = MFMA16(*(const bf16x8*)(wb), hA[kk], accr);
          accz = MFMA16(*(const bf16x8*)(wb + 8192), hA[kk], accz);
          acchn = MFMA16(*(const bf16x8*)(wb + 16384), hA[kk], acchn);
        }
        wait_flags(zflag, NPST, t, false);  // z_{t-1}; h-acquire already inv'd zb
        const __bf16* zp = zb + (size_t)rb * SS + q8;
        bf16x8 zA[8];
#pragma unroll
        for (int kk = 0; kk < 8; ++kk) zA[kk] = *(const bf16x8*)(zp + kk * 32);
#pragma unroll
        for (int kk = 0; kk < 8; ++kk) {
          const __bf16* wb = smem + 24576 + ((size_t)kk * 8 + col8) * 32 + swq * 8;
          accr = MFMA16(*(const bf16x8*)(wb), zA[kk], accr);
          accz = MFMA16(*(const bf16x8*)(wb + 2048), zA[kk], accz);
          accin = MFMA16(*(const bf16x8*)(wb + 4096), zA[kk], accin);
        }
      }
      __bf16* hw = hbL[(t + 1) & 1];
#pragma unroll
      for (int r = 0; r < 4; ++r) {
        float rg = fsig(accr[r] + brs[r]);
        float zg = fsig(accz[r] + bzs[r]);
        float ng = ftanh(accin[r] + bin4[r] + rg * (acchn[r] + bhn4[r]));
        hcarry[r] = (1.f - zg) * ng + zg * hcarry[r];
      }
      if (q < 2) st8(hw + (size_t)rb * DD + colw, pack4(hcarry));  // one 8B WT store
      // signal: drain handoff stores, barrier, one uncontended flag store
      asm volatile("s_waitcnt vmcnt(0)" ::: "memory");
      __syncthreads();
      if (tid == 0)
        __hip_atomic_store(hflag + blk, t + 1, __ATOMIC_RELAXED, __HIP_MEMORY_SCOPE_AGENT);
    }
    // tail: archive h_{255}
    if (q < 2)
      __builtin_nontemporal_store(
          pack4(hcarry),
          (unsigned long long*)(h_all + (size_t)(TT - 1) * BB * DD + (size_t)rb * DD + colw));
  } else {
    int p = blk - NGRU, cp0 = p * 16;
    int swq = (q + ((n15 >> 1) & 3)) & 3;
    // ---- stage Wm/Wv h-part (2 x 16 cols x K=1024) into LDS (64 KB)
    for (int u = tid; u < 4096; u += 256) {
      int qq = u & 3, col = (u >> 2) & 15, kk = (u >> 6) & 31, mv = u >> 11;
      int sq = (qq + ((col >> 1) & 3)) & 3;
      const float* src = (mv ? Wv : Wm) + ((size_t)(cp0 + col)) * (II + DD) + II + kk * 32 + qq * 8;
      *(bf16x8*)(smem + ((((mv * 32 + kk) * 16 + col) * 4) + sq) * 8) = ld8f(src);
    }
    __syncthreads();

    int c4 = cp0 + q * 4;  // this lane's 4 z-cols (all valid)
    f32x4 bmv = *(const f32x4*)(bm + c4);
    f32x4 bvv = *(const f32x4*)(bv + c4);
    f32x4 zsPrev = {};

    for (int t = 0; t < TT; ++t) {
      // prefetch t-dependent inputs (independent of h_t) BEFORE the wait
      size_t base = ((size_t)t * BB + rb) * SS + c4;
      f32x4 nz = *(const f32x4*)(noise + base);
      bf16x4 xm4 = *(const bf16x4*)(xm + base);
      bf16x4 xv4 = *(const bf16x4*)(xv + base);

      wait_flags(hflag, NGRU, t + 1, true);  // h_t ready
      const __bf16* hp = hbL[(t + 1) & 1] + (size_t)rb * DD + q8;
      bf16x8 hA[32];
#pragma unroll
      for (int kk = 0; kk < 32; ++kk) hA[kk] = *(const bf16x8*)(hp + kk * 32);
      // archive z_{t-1}: behind hA loads in FIFO; completes during the GEMM
      if (t > 0)
        __builtin_nontemporal_store(
            pack4(zsPrev),
            (unsigned long long*)(z_all + ((size_t)(t - 1) * BB + rb) * SS + c4));
      f32x4 am = {}, av = {};
#pragma unroll
      for (int kk = 0; kk < 32; ++kk) {
        const __bf16* wb = smem + ((size_t)kk * 16 + n15) * 32 + swq * 8;
        am = MFMA16(*(const bf16x8*)(wb), hA[kk], am);
        av = MFMA16(*(const bf16x8*)(wb + 16384), hA[kk], av);
      }
#pragma unroll
      for (int r = 0; r < 4; ++r) {
        float mean = am[r] + bmv[r] + (float)xm4[r];
        float vr = av[r] + bvv[r] + (float)xv4[r];
        float sd = __expf(0.5f * vr);
        zsPrev[r] = nz[r] * sd + mean;
      }
      st8(zb + (size_t)rb * SS + c4, pack4(zsPrev));  // one 8B WT store
      asm volatile("s_waitcnt vmcnt(0)" ::: "memory");
      __syncthreads();
      if (tid == 0)
        __hip_atomic_store(zflag + p, t + 1, __ATOMIC_RELAXED, __HIP_MEMORY_SCOPE_AGENT);
    }
    // tail: archive z_{255}
    __builtin_nontemporal_store(
        pack4(zsPrev), (unsigned long long*)(z_all + ((size_t)(TT - 1) * BB + rb) * SS + c4));
  }
}

// ---------------------------------------------------------------------------
// Decoder layer 0: elu([h_all | z_all] @ W0.T + b0) -> a0 (ws), K=1280.
// ---------------------------------------------------------------------------
__global__ __launch_bounds__(256, 2) void k_dec0(const char* __restrict__ doutc,
                                                 const char* __restrict__ ws,
                                                 const float* __restrict__ b0,
                                                 __bf16* __restrict__ C) {
  const __bf16* h_all = (const __bf16*)doutc;
  const __bf16* z_all = (const __bf16*)(ws + OFF_Z);
  const __bf16* W0b = (const __bf16*)(doutc + DO_WB0);
  int m0 = blockIdx.x * 128, n0 = blockIdx.y * 128;
  int tid = threadIdx.x, lane = tid & 63, w = tid >> 6;
  int wm = w >> 1, wn = w & 1;
  int n15 = lane & 15, q8 = (lane >> 4) * 8, q4 = (lane >> 4) * 4;

  const __bf16* hrow[4];
  const __bf16* zrow[4];
  const __bf16* brow[4];
#pragma unroll
  for (int i = 0; i < 4; ++i) {
    int row = m0 + wm * 64 + i * 16 + n15;  // m = b*256 + t
    int b = row >> 8, tq = row & 255;
    hrow[i] = h_all + ((size_t)tq * BB + b) * DD + q8;
    zrow[i] = z_all + ((size_t)tq * BB + b) * SS + q8;
  }
#pragma unroll
  for (int j = 0; j < 4; ++j)
    brow[j] = W0b + (size_t)(n0 + wn * 64 + j * 16 + n15) * (DD + SS) + q8;

  f32x4 acc[4][4] = {};
  for (int k = 0; k < DD + SS; k += 32) {
    bf16x8 af[4], bfv[4];
#pragma unroll
    for (int i = 0; i < 4; ++i)
      af[i] = (k < DD) ? *(const bf16x8*)(hrow[i] + k) : *(const bf16x8*)(zrow[i] + k - DD);
#pragma unroll
    for (int j = 0; j < 4; ++j) bfv[j] = *(const bf16x8*)(brow[j] + k);
#pragma unroll
    for (int i = 0; i < 4; ++i)
#pragma unroll
      for (int j = 0; j < 4; ++j) acc[i][j] = MFMA16(af[i], bfv[j], acc[i][j]);
  }
#pragma unroll
  for (int i = 0; i < 4; ++i) {
    int mr = m0 + wm * 64 + i * 16 + q4;
#pragma unroll
    for (int j = 0; j < 4; ++j) {
      int c = n0 + wn * 64 + j * 16 + n15;
      float bb = b0[c];
#pragma unroll
      for (int r = 0; r < 4; ++r) {
        float v = acc[i][j][r] + bb;
        v = v > 0.f ? v : (__expf(v) - 1.f);
        C[(size_t)(mr + r) * HH + c] = (__bf16)v;
      }
    }
  }
}

// ---------------------------------------------------------------------------
// Decoder mid layer: C = elu(A @ W.T + b), K = N = 1024; W pre-converted bf16.
// If W3src != nullptr, also stage W3 -> bf16 at W3dst (z_all region is dead
// after dec0; dec3 consumes the bf16 copy). 512*1024/8 = 65536 thread-slots.
// ---------------------------------------------------------------------------
__global__ __launch_bounds__(256, 2) void k_dec_mid(const __bf16* __restrict__ A,
                                                    const __bf16* __restrict__ W,
                                                    const float* __restrict__ bias,
                                                    __bf16* __restrict__ C,
                                                    const float* __restrict__ W3src,
                                                    __bf16* __restrict__ W3dst) {
  if (W3src) {
    size_t flat = (size_t)blockIdx.y * 128 + blockIdx.x;  // 0..1023
    if (flat < 256) {
      size_t g = (flat * 256 + threadIdx.x) * 8;  // < 524288
      *(bf16x8*)(W3dst + g) = ld8f(W3src + g);
    }
  }
  int m0 = blockIdx.x * 128, n0 = blockIdx.y * 128;
  int tid = threadIdx.x, lane = tid & 63, w = tid >> 6;
  int wm = w >> 1, wn = w & 1;
  int n15 = lane & 15, q8 = (lane >> 4) * 8, q4 = (lane >> 4) * 4;

  const __bf16* arow[4];
  const __bf16* brow[4];
#pragma unroll
  for (int i = 0; i < 4; ++i) arow[i] = A + (size_t)(m0 + wm * 64 + i * 16 + n15) * DD + q8;
#pragma unroll
  for (int j = 0; j < 4; ++j) brow[j] = W + (size_t)(n0 + wn * 64 + j * 16 + n15) * DD + q8;

  f32x4 acc[4][4] = {};
  for (int k = 0; k < DD; k += 32) {
    bf16x8 af[4], bfv[4];
#pragma unroll
    for (int i = 0; i < 4; ++i) af[i] = *(const bf16x8*)(arow[i] + k);
#pragma unroll
    for (int j = 0; j < 4; ++j) bfv[j] = *(const bf16x8*)(brow[j] + k);
#pragma unroll
    for (int i = 0; i < 4; ++i)
#pragma unroll
      for (int j = 0; j < 4; ++j) acc[i][j] = MFMA16(af[i], bfv[j], acc[i][j]);
  }
#pragma unroll
  for (int i = 0; i < 4; ++i) {
    int mr = m0 + wm * 64 + i * 16 + q4;
#pragma unroll
    for (int j = 0; j < 4; ++j) {
      int c = n0 + wn * 64 + j * 16 + n15;
      float bb = bias[c];
#pragma unroll
      for (int r = 0; r < 4; ++r) {
        float v = acc[i][j][r] + bb;
        v = v > 0.f ? v : (__expf(v) - 1.f);
        C[(size_t)(mr + r) * HH + c] = (__bf16)v;
      }
    }
  }
}

// ---------------------------------------------------------------------------
// Decoder layer 3 + output assembly (fp32 outputs); W3 consumed as bf16.
// ---------------------------------------------------------------------------
__global__ __launch_bounds__(256, 2) void k_dec3(const __bf16* __restrict__ A,
                                                 const __bf16* __restrict__ W3b,
                                                 const float* __restrict__ b3,
                                                 const float* __restrict__ x,
                                                 float* __restrict__ outd,
                                                 float* __restrict__ outh) {
  int m0 = blockIdx.x * 128, n0 = blockIdx.y * 128;
  int tid = threadIdx.x, lane = tid & 63, w = tid >> 6;
  int wm = w >> 1, wn = w & 1;
  int n15 = lane & 15, q8 = (lane >> 4) * 8, q4 = (lane >> 4) * 4;

  const __bf16* arow[4];
  const __bf16* brow[4];
#pragma unroll
  for (int i = 0; i < 4; ++i) arow[i] = A + (size_t)(m0 + wm * 64 + i * 16 + n15) * HH + q8;
#pragma unroll
  for (int j = 0; j < 4; ++j) brow[j] = W3b + (size_t)(n0 + wn * 64 + j * 16 + n15) * HH + q8;

  f32x4 acc[4][4] = {};
  for (int k = 0; k < HH; k += 32) {
    bf16x8 af[4], bfv[4];
#pragma unroll
    for (int i = 0; i < 4; ++i) af[i] = *(const bf16x8*)(arow[i] + k);
#pragma unroll
    for (int j = 0; j < 4; ++j) bfv[j] = *(const bf16x8*)(brow[j] + k);
#pragma unroll
    for (int i = 0; i < 4; ++i)
#pragma unroll
      for (int j = 0; j < 4; ++j) acc[i][j] = MFMA16(af[i], bfv[j], acc[i][j]);
  }
#pragma unroll
  for (int i = 0; i < 4; ++i) {
    int mr = m0 + wm * 64 + i * 16 + q4;
#pragma unroll
    for (int j = 0; j < 4; ++j) {
      int c = n0 + wn * 64 + j * 16 + n15;
      float b3v = b3[c];
#pragma unroll
      for (int r = 0; r < 4; ++r) {
        int mm = mr + r;
        int b = mm >> 8, tq = mm & 255;
        float dv = acc[i][j][r] + b3v;
        if (tq < 255) {
          outd[((size_t)b * 255 + tq) * II + c] = dv;
          outh[((size_t)b * TT + tq + 1) * II + c] = x[((size_t)b * TT + tq) * II + c] + dv;
        }
        if (tq == 0) outh[((size_t)b * TT) * II + c] = x[((size_t)b * TT) * II + c];
      }
    }
  }
}

// ---------------------------------------------------------------------------
extern "C" void kernel_launch(void* const* d_in, const int* in_sizes, int n_in,
                              void* d_out, int out_size, void* d_ws, size_t ws_size,
                              hipStream_t stream) {
  const float* x = (const float*)d_in[0];
  const float* noise = (const float*)d_in[1];
  const float* W_ih = (const float*)d_in[2];
  const float* W_hh = (const float*)d_in[3];
  const float* b_ih = (const float*)d_in[4];
  const float* b_hh = (const float*)d_in[5];
  const float* Wm = (const float*)d_in[6];
  const float* bm = (const float*)d_in[7];
  const float* Wv = (const float*)d_in[8];
  const float* bv = (const float*)d_in[9];
  const float* dW0 = (const float*)d_in[10];
  const float* db0 = (const float*)d_in[11];
  const float* dW1 = (const float*)d_in[12];
  const float* db1 = (const float*)d_in[13];
  const float* dW2 = (const float*)d_in[14];
  const float* db2 = (const float*)d_in[15];
  const float* dW3 = (const float*)d_in[16];
  const float* db3 = (const float*)d_in[17];

  char* ws = (char*)d_ws;
  char* doutc = (char*)d_out;
  __bf16* a0 = (__bf16*)(ws + OFF_A);        // dec0 out
  __bf16* a1 = (__bf16*)doutc;               // dec1 out (over dead h_all)
  __bf16* a2 = (__bf16*)(ws + OFF_A);        // dec2 out (over dead a0)
  __bf16* w3b = (__bf16*)(ws + OFF_Z);       // W3 bf16 copy (over dead z archive)

  // 1) x-dependent posterior halves + flag zeroing + dec-weight bf16 staging
  k_xmv<<<dim3(256, 8), 256, 0, stream>>>(x, Wm, Wv, dW0, dW1, dW2, doutc, ws);

  // 2) persistent scan: 128 GRU + 16 posterior blocks, all weights in LDS
  k_scan<<<NGRU + NPST, 256, 0, stream>>>(W_ih, W_hh, b_ih, b_hh, Wm, bm, Wv, bv, noise, ws,
                                          doutc);

  // 3) decoder (W0..W2 bf16 from d_out scratch; W3 staged bf16 during dec1)
  k_dec0<<<dim3(128, 8), 256, 0, stream>>>(doutc, ws, db0, a0);
  k_dec_mid<<<dim3(128, 8), 256, 0, stream>>>(a0, (const __bf16*)(doutc + DO_WB1), db1, a1,
                                              dW3, w3b);
  k_dec_mid<<<dim3(128, 8), 256, 0, stream>>>(a1, (const __bf16*)(doutc + DO_WB2), db2, a2,
                                              nullptr, nullptr);
  k_dec3<<<dim3(128, 4), 256, 0, stream>>>(a2, w3b, db3, x, (float*)doutc,
                                           (float*)doutc + OUTD_ELEMS);
}